// Round 7
// baseline (2037.499 us; speedup 1.0000x reference)
//
#include <hip/hip_runtime.h>

// ---------------------------------------------------------------------------
// SPADE-style encoder.
// conv3: bf16 MFMA implicit-GEMM, block = 1 image row (128 px) x 512 co,
//        8 waves, wave tile 64x128. R7: explicit tap-level register
//        double-buffer for the B operand (weights) so L2 latency hides
//        under the previous tap's MFMA cluster (R6 was L2-latency-bound,
//        MfmaUtil 13%). Fused tanh + segmap region pooling.
// convT: bf16 MFMA per-parity-class GEMM, IN stats+apply writes Xpad.
// conv0/conv1/conv2 + their instance-norms still fp32 vector.
// ---------------------------------------------------------------------------

#define B 8

typedef __attribute__((ext_vector_type(8))) short short8;
typedef __attribute__((ext_vector_type(4))) float f32x4;

static __device__ __forceinline__ unsigned short f2bf(float f) {
  union { float f; unsigned u; } v;
  v.f = f;
  unsigned r = v.u + 0x7fffu + ((v.u >> 16) & 1u);
  return (unsigned short)(r >> 16);
}
static __device__ __forceinline__ float bf2f(unsigned short h) {
  union { unsigned u; float f; } v;
  v.u = (unsigned)h << 16;
  return v.f;
}
static __device__ __forceinline__ float tanh_fast(float x) {
  float ax = fabsf(x);
  ax = fminf(ax, 20.f);
  const float e = __expf(-2.f * ax);
  const float t = (1.f - e) / (1.f + e);
  return __builtin_copysignf(t, x);
}

// ---------------- conv0: 3->32, reflect pad 1, 256x256 ----------------
__global__ __launch_bounds__(256) void conv0_kernel(
    const float* __restrict__ in, const float* __restrict__ w,
    const float* __restrict__ bias, float* __restrict__ out) {
  __shared__ float sw[32 * 27 + 32];
  for (int i = threadIdx.x; i < 32 * 27; i += 256) sw[i] = w[i];
  if (threadIdx.x < 32) sw[32 * 27 + threadIdx.x] = bias[threadIdx.x];
  __syncthreads();
  const int b = blockIdx.y;
  const int p = blockIdx.x * 256 + threadIdx.x;
  const int y = p >> 8, x = p & 255;
  const float* inb = in + (size_t)b * 3 * 65536;
  float v[27];
#pragma unroll
  for (int c = 0; c < 3; ++c) {
#pragma unroll
    for (int ky = 0; ky < 3; ++ky) {
      int iy = y + ky - 1;
      iy = iy < 0 ? -iy : (iy > 255 ? 510 - iy : iy);
#pragma unroll
      for (int kx = 0; kx < 3; ++kx) {
        int ix = x + kx - 1;
        ix = ix < 0 ? -ix : (ix > 255 ? 510 - ix : ix);
        v[c * 9 + ky * 3 + kx] = inb[c * 65536 + iy * 256 + ix];
      }
    }
  }
  float* ob = out + (size_t)b * 32 * 65536 + p;
#pragma unroll
  for (int co = 0; co < 32; ++co) {
    float a = sw[32 * 27 + co];
#pragma unroll
    for (int k = 0; k < 27; ++k) a = fmaf(v[k], sw[co * 27 + k], a);
    ob[(size_t)co * 65536] = a;
  }
}

// ---------------- fused instance-norm + leaky relu (in place, fp32) ----------
__global__ __launch_bounds__(256) void inorm_lrelu_kernel(float* __restrict__ x,
                                                          int HW) {
  const size_t base = (size_t)blockIdx.x * HW;
  float4* p = (float4*)(x + base);
  const int n4 = HW >> 2;
  float s = 0.f, q = 0.f;
  for (int i = threadIdx.x; i < n4; i += 256) {
    float4 v = p[i];
    s += (v.x + v.y) + (v.z + v.w);
    q += (v.x * v.x + v.y * v.y) + (v.z * v.z + v.w * v.w);
  }
  __shared__ float rs[256], rq[256];
  rs[threadIdx.x] = s;
  rq[threadIdx.x] = q;
  __syncthreads();
  for (int st = 128; st > 0; st >>= 1) {
    if (threadIdx.x < st) {
      rs[threadIdx.x] += rs[threadIdx.x + st];
      rq[threadIdx.x] += rq[threadIdx.x + st];
    }
    __syncthreads();
  }
  const float m = rs[0] / (float)HW;
  float var = rq[0] / (float)HW - m * m;
  var = var < 0.f ? 0.f : var;
  const float r = rsqrtf(var + 1e-5f);
  for (int i = threadIdx.x; i < n4; i += 256) {
    float4 v = p[i];
    v.x = (v.x - m) * r; v.x = v.x >= 0.f ? v.x : 0.2f * v.x;
    v.y = (v.y - m) * r; v.y = v.y >= 0.f ? v.y : 0.2f * v.y;
    v.z = (v.z - m) * r; v.z = v.z >= 0.f ? v.z : 0.2f * v.z;
    v.w = (v.w - m) * r; v.w = v.w >= 0.f ? v.w : 0.2f * v.w;
    p[i] = v;
  }
}

// ---------------- 3x3 stride-2 zero-pad-1 conv, 32 co per block ----------------
template <int CIN, int COUT, int HIN>
__global__ __launch_bounds__(256) void conv_s2_kernel(
    const float* __restrict__ in, const float* __restrict__ w,
    const float* __restrict__ bias, float* __restrict__ out) {
  constexpr int HOUT = HIN / 2;
  const int b = blockIdx.z;
  const int co0 = blockIdx.y * 32;
  const int p = blockIdx.x * 256 + threadIdx.x;
  const int oy = p / HOUT, ox = p % HOUT;
  float acc[32];
#pragma unroll
  for (int i = 0; i < 32; ++i) acc[i] = bias[co0 + i];
  const float* inb = in + (size_t)b * CIN * HIN * HIN;
  const int iy0 = 2 * oy - 1, ix0 = 2 * ox - 1;
  for (int ci = 0; ci < CIN; ++ci) {
    float v[9];
    const float* ip = inb + (size_t)ci * HIN * HIN;
#pragma unroll
    for (int ky = 0; ky < 3; ++ky) {
      const int iy = iy0 + ky;
      const bool yok = (unsigned)iy < (unsigned)HIN;
#pragma unroll
      for (int kx = 0; kx < 3; ++kx) {
        const int ix = ix0 + kx;
        const bool ok = yok && ((unsigned)ix < (unsigned)HIN);
        v[ky * 3 + kx] = ok ? ip[iy * HIN + ix] : 0.f;
      }
    }
    const float* wp = w + ((size_t)co0 * CIN + ci) * 9;
#pragma unroll
    for (int co = 0; co < 32; ++co) {
#pragma unroll
      for (int k = 0; k < 9; ++k)
        acc[co] = fmaf(v[k], wp[(size_t)co * CIN * 9 + k], acc[co]);
    }
  }
  float* ob = out + ((size_t)b * COUT + co0) * HOUT * HOUT + p;
#pragma unroll
  for (int co = 0; co < 32; ++co) ob[(size_t)co * HOUT * HOUT] = acc[co];
}

// -------- transpose x2: fp32 [b][128][4096] -> X2p bf16 [b][65][65][128] ----
__global__ __launch_bounds__(256) void transpose_x2_kernel(
    const float* __restrict__ x2, unsigned short* __restrict__ X2p) {
  const int b = blockIdx.y;
  const int p0 = (blockIdx.x & 63) * 64;
  const int ci0 = (blockIdx.x >> 6) * 64;
  __shared__ unsigned short T[64][66];
  const float* src = x2 + (size_t)b * 128 * 4096;
  const int t = threadIdx.x;
#pragma unroll
  for (int r = 0; r < 16; ++r) {
    const int ci_l = r * 4 + (t >> 6);
    const int p_l = t & 63;
    T[ci_l][p_l] = f2bf(src[(size_t)(ci0 + ci_l) * 4096 + p0 + p_l]);
  }
  __syncthreads();
  unsigned short* dst = X2p + (size_t)b * 65 * 65 * 128;
#pragma unroll
  for (int r = 0; r < 2; ++r) {
    const int p_l = r * 32 + (t >> 3);
    const int c0 = (t & 7) * 8;
    union { short8 v; unsigned short u[8]; } pk;
#pragma unroll
    for (int j = 0; j < 8; ++j) pk.u[j] = T[c0 + j][p_l];
    const int p = p0 + p_l;
    const int yy = p >> 6, xx = p & 63;
    *(short8*)(dst + ((size_t)yy * 65 + xx) * 128 + ci0 + c0) = pk.v;
  }
}

// ---------------- zero pad row 64 / col 64 of X2p ----------------
__global__ __launch_bounds__(256) void zpad_x2_kernel(unsigned short* __restrict__ X2p) {
  const int b = blockIdx.x;
  unsigned short* Xb = X2p + (size_t)b * 65 * 65 * 128;
  for (int i = threadIdx.x; i < 129 * 128; i += 256) {
    const int j = i >> 7, ci = i & 127;
    size_t off;
    if (j < 65) off = ((size_t)64 * 65 + j) * 128 + ci;
    else off = ((size_t)(j - 65) * 65 + 64) * 128 + ci;
    Xb[off] = 0;
  }
}

// -------- weight repack: wt [256][128][3][3] fp32 -> Wtb [9][256][128] bf16 --
__global__ __launch_bounds__(256) void wtprep_kernel(const float* __restrict__ wt,
                                                     unsigned short* __restrict__ Wtb) {
  const int i = blockIdx.x * 256 + threadIdx.x;
  if (i >= 9 * 256 * 128) return;
  const int ci = i & 127, co = (i >> 7) & 255, tap = i >> 15;
  Wtb[i] = f2bf(wt[((size_t)co * 128 + ci) * 9 + tap]);
}

// ---------------- convT as bf16 MFMA per-parity-class GEMM ----------------
__global__ __launch_bounds__(256, 3) void convt_mfma_kernel(
    const unsigned short* __restrict__ X2p, const unsigned short* __restrict__ Wtb,
    const float* __restrict__ bt, unsigned short* __restrict__ Y) {
  const int raw = blockIdx.x;
  const int swz = (raw & 7) * 256 + (raw >> 3);
  const int b = swz >> 8;
  const int rem = swz & 255;
  const int cls = rem >> 6;
  const int sy = rem & 63;
  const int py = cls & 1, px = cls >> 1;

  const int kyA = py ? 0 : 1, kxA = px ? 0 : 1;
  int tk[4], tdy[4], tdx[4];
  int ntaps = 0;
  tk[ntaps] = kyA * 3 + kxA; tdy[ntaps] = 0; tdx[ntaps] = 0; ++ntaps;
  if (px) { tk[ntaps] = kyA * 3 + 2; tdy[ntaps] = 0; tdx[ntaps] = 1; ++ntaps; }
  if (py) { tk[ntaps] = 6 + kxA; tdy[ntaps] = 1; tdx[ntaps] = 0; ++ntaps; }
  if (py && px) { tk[ntaps] = 8; tdy[ntaps] = 1; tdx[ntaps] = 1; ++ntaps; }

  constexpr int CS = 36;
  constexpr int BUFN = 2 * 65 * CS;
  __shared__ unsigned short As2[2 * BUFN];

  const int t = threadIdx.x;
  const int lane = t & 63;
  const int wn = t >> 6;
  const int lg = lane >> 4, lr = lane & 15;
  const int co_w = wn * 64;

  const unsigned short* Xb = X2p + (size_t)b * 65 * 65 * 128;

  int dof0, dof1, dof2;
  const unsigned short *sp0, *sp1, *sp2;
  bool sv2;
  {
    const int i0 = t, i1 = t + 256, i2 = t + 512;
    const int r0 = i0 / 260, c0_ = (i0 % 260) >> 2, h0 = i0 & 3;
    const int r1 = i1 / 260, c1_ = (i1 % 260) >> 2, h1 = i1 & 3;
    sv2 = i2 < 520;
    const int i2c = sv2 ? i2 : 512;
    const int r2 = i2c / 260, c2_ = (i2c % 260) >> 2, h2 = i2c & 3;
    dof0 = (r0 * 65 + c0_) * CS + h0 * 8;
    dof1 = (r1 * 65 + c1_) * CS + h1 * 8;
    dof2 = (r2 * 65 + c2_) * CS + h2 * 8;
    sp0 = Xb + ((size_t)(sy + r0) * 65 + c0_) * 128 + h0 * 8;
    sp1 = Xb + ((size_t)(sy + r1) * 65 + c1_) * 128 + h1 * 8;
    sp2 = Xb + ((size_t)(sy + r2) * 65 + c2_) * 128 + h2 * 8;
  }

  f32x4 acc[4][4];
#pragma unroll
  for (int mt = 0; mt < 4; ++mt)
#pragma unroll
    for (int nt = 0; nt < 4; ++nt) {
      f32x4 z = {0.f, 0.f, 0.f, 0.f};
      acc[mt][nt] = z;
    }

  {
    const short8 a = *(const short8*)sp0;
    const short8 bq = *(const short8*)sp1;
    short8 cq;
    if (sv2) cq = *(const short8*)sp2;
    *(short8*)(As2 + dof0) = a;
    *(short8*)(As2 + dof1) = bq;
    if (sv2) *(short8*)(As2 + dof2) = cq;
  }
  __syncthreads();

  for (int c8 = 0; c8 < 4; ++c8) {
    short8 n0, n1, n2;
    if (c8 < 3) {
      const int cn = (c8 + 1) * 32;
      n0 = *(const short8*)(sp0 + cn);
      n1 = *(const short8*)(sp1 + cn);
      if (sv2) n2 = *(const short8*)(sp2 + cn);
    }
    const unsigned short* Ab = As2 + (c8 & 1) * BUFN;
    for (int tp = 0; tp < ntaps; ++tp) {
      const int dy = tdy[tp], dx = tdx[tp];
      short8 af[4];
#pragma unroll
      for (int mt = 0; mt < 4; ++mt)
        af[mt] = *(const short8*)(Ab + (dy * 65 + mt * 16 + lr + dx) * CS + lg * 8);
      const unsigned short* wt_ =
          Wtb + ((size_t)(tk[tp] * 256 + co_w + lr) * 128) + c8 * 32 + lg * 8;
#pragma unroll
      for (int nt = 0; nt < 4; ++nt) {
        const short8 bf = *(const short8*)(wt_ + (size_t)nt * 16 * 128);
#pragma unroll
        for (int mt = 0; mt < 4; ++mt)
          acc[mt][nt] = __builtin_amdgcn_mfma_f32_16x16x32_bf16(
              af[mt], bf, acc[mt][nt], 0, 0, 0);
      }
    }
    if (c8 < 3) {
      unsigned short* Db = As2 + ((c8 + 1) & 1) * BUFN;
      *(short8*)(Db + dof0) = n0;
      *(short8*)(Db + dof1) = n1;
      if (sv2) *(short8*)(Db + dof2) = n2;
    }
    __syncthreads();
  }

  const int oy = 2 * sy + py;
  unsigned short* Yb = Y + ((size_t)b * 16384 + (size_t)oy * 128 + px) * 256;
  float bco[4];
#pragma unroll
  for (int nt = 0; nt < 4; ++nt) bco[nt] = bt[co_w + nt * 16 + lr];
#pragma unroll
  for (int mt = 0; mt < 4; ++mt) {
#pragma unroll
    for (int r = 0; r < 4; ++r) {
      const int sx = mt * 16 + lg * 4 + r;
      unsigned short* yp = Yb + (size_t)(2 * sx) * 256 + co_w + lr;
#pragma unroll
      for (int nt = 0; nt < 4; ++nt)
        yp[nt * 16] = f2bf(acc[mt][nt][r] + bco[nt]);
    }
  }
}

// ---------------- instance-norm stats over pixel-major Y ----------------
__global__ __launch_bounds__(256) void inorm_stats_kernel(
    const unsigned short* __restrict__ Y, float* __restrict__ ssum,
    float* __restrict__ ssq) {
  const int b = blockIdx.y, sl = blockIdx.x, c = threadIdx.x;
  const unsigned short* p = Y + ((size_t)b * 16384 + (size_t)sl * 1024) * 256 + c;
  float s = 0.f, q = 0.f;
  for (int i = 0; i < 1024; ++i) {
    const float v = bf2f(p[(size_t)i * 256]);
    s += v;
    q += v * v;
  }
  atomicAdd(&ssum[b * 256 + c], s);
  atomicAdd(&ssq[b * 256 + c], q);
}

// ------- apply IN + LReLU to Y, write bf16 into Xpad interior -------
__global__ __launch_bounds__(256) void inorm_apply_kernel(
    const unsigned short* __restrict__ Y, const float* __restrict__ ssum,
    const float* __restrict__ ssq, unsigned short* __restrict__ Xpad) {
  const int b = blockIdx.y, sl = blockIdx.x, c = threadIdx.x;
  const float m = ssum[b * 256 + c] * (1.f / 16384.f);
  float var = ssq[b * 256 + c] * (1.f / 16384.f) - m * m;
  var = var < 0.f ? 0.f : var;
  const float r = rsqrtf(var + 1e-5f);
  const unsigned short* p = Y + ((size_t)b * 16384 + (size_t)sl * 1024) * 256 + c;
  unsigned short* dst = Xpad + (size_t)b * 130 * 130 * 256 + c;
  for (int i = 0; i < 1024; ++i) {
    const int pix = sl * 1024 + i;
    const int yy = pix >> 7, xx = pix & 127;
    float v = bf2f(p[(size_t)i * 256]);
    v = (v - m) * r;
    v = v >= 0.f ? v : 0.2f * v;
    dst[((size_t)(yy + 1) * 130 + (xx + 1)) * 256] = f2bf(v);
  }
}

// ---------------- reflect borders of Xpad: rows then cols ----------------
__global__ __launch_bounds__(256) void pad_rows_kernel(unsigned short* __restrict__ Xp) {
  const int b = blockIdx.x >> 1, side = blockIdx.x & 1;
  unsigned short* Xb = Xp + (size_t)b * 130 * 130 * 256;
  const int dr = side ? 129 : 0, sr = side ? 127 : 2;
  for (int i = threadIdx.x; i < 4096; i += 256) {
    const int c = 1 + (i >> 5), o = (i & 31) * 8;
    *(short8*)(Xb + ((size_t)dr * 130 + c) * 256 + o) =
        *(const short8*)(Xb + ((size_t)sr * 130 + c) * 256 + o);
  }
}
__global__ __launch_bounds__(256) void pad_cols_kernel(unsigned short* __restrict__ Xp) {
  const int b = blockIdx.x >> 1, side = blockIdx.x & 1;
  unsigned short* Xb = Xp + (size_t)b * 130 * 130 * 256;
  const int dc = side ? 129 : 0, sc = side ? 127 : 2;
  for (int i = threadIdx.x; i < 130 * 32; i += 256) {
    const int r = i >> 5, o = (i & 31) * 8;
    *(short8*)(Xb + ((size_t)r * 130 + dc) * 256 + o) =
        *(const short8*)(Xb + ((size_t)r * 130 + sc) * 256 + o);
  }
}

// ------ weight repack: w3 [512][256][9] fp32 -> Wb [9][512][256] bf16 ------
__global__ __launch_bounds__(256) void wprep_kernel(const float* __restrict__ w3,
                                                    unsigned short* __restrict__ Wb) {
  const int i = blockIdx.x * 256 + threadIdx.x;
  if (i >= 9 * 512 * 256) return;
  const int ci = i & 255, co = (i >> 8) & 511, tap = i >> 17;
  Wb[i] = f2bf(w3[((size_t)co * 256 + ci) * 9 + tap]);
}

// ---------------- label extraction + counts from one-hot segmap ----------------
__global__ __launch_bounds__(256) void label_kernel(
    const float* __restrict__ segmap, int* __restrict__ labels,
    float* __restrict__ cnt) {
  const int b = blockIdx.y;
  const int p = blockIdx.x * 256 + threadIdx.x;
  const int i = p >> 7, j = p & 127;
  const float* sp = segmap + (size_t)b * 19 * 65536 + (2 * i) * 256 + 2 * j;
  int lab = 0;
#pragma unroll
  for (int s = 0; s < 19; ++s)
    if (sp[(size_t)s * 65536] != 0.f) lab = s;
  labels[b * 16384 + p] = lab;
  atomicAdd(&cnt[b * 19 + lab], 1.0f);
}

// ---------------- conv3: bf16 MFMA implicit GEMM + tanh + region pool --------
// Block = 512 threads (8 waves) = one image row (128 px) x ALL 512 co.
// Wave grid 2Mx4N, wave tile 64px x 128co, acc 4x8 f32x4 = 128 AGPR.
// Per 32-ci chunk: stage 3x130 halo window once (serves all 9 taps).
// R7: B-operand (weights) tap-level register double-buffer bfb[2][8]:
// tap t+1's 8 L2 loads issue BEFORE tap t's 32-MFMA cluster; chunks
// alternate phase P so all bfb indices are compile-time static.
__global__ __launch_bounds__(512, 2) void conv3_mfma_pool_kernel(
    const unsigned short* __restrict__ Xpad, const unsigned short* __restrict__ Wb,
    const float* __restrict__ bias, const int* __restrict__ labels,
    float* __restrict__ sums) {
  // XCD swizzle: 1024 = 8 XCDs x 128 -> one batch per XCD
  const int raw = blockIdx.x;
  const int swz = (raw & 7) * 128 + (raw >> 3);
  const int b = swz >> 7;
  const int y = swz & 127;

  constexpr int RS = 36;              // LDS col-entry stride (72B)
  constexpr int BUFN = 3 * 130 * RS;  // 14040 ushort per buffer
  __shared__ unsigned short Asw[2 * BUFN];  // 56.2 KB
  __shared__ float lsum[19 * 512];          // 38.9 KB

  const int t = threadIdx.x;
  const int lane = t & 63;
  const int wave = t >> 6;     // 0..7
  const int wm = wave >> 2;    // 0..1: M group (64 px)
  const int wn = wave & 3;     // 0..3: N group (128 co)
  const int lg = lane >> 4, lr = lane & 15;
  const int co_w = wn * 128;

  for (int i = t; i < 19 * 512; i += 512) lsum[i] = 0.f;

  const unsigned short* Xb = Xpad + (size_t)b * 130 * 130 * 256;

  // staging: 1560 chunks = r(3) x c(130) x h(4)
  int dof0, dof1, dof2, dof3;
  const unsigned short *sp0, *sp1, *sp2, *sp3;
  bool sv3;
  {
    const int i0 = t, i1 = t + 512, i2 = t + 1024, i3 = t + 1536;
    const int r0 = i0 / 520, c0 = (i0 % 520) >> 2, h0 = i0 & 3;
    const int r1 = i1 / 520, c1 = (i1 % 520) >> 2, h1 = i1 & 3;
    const int r2 = i2 / 520, c2 = (i2 % 520) >> 2, h2 = i2 & 3;
    sv3 = i3 < 1560;
    const int i3c = sv3 ? i3 : 1536;
    const int r3 = i3c / 520, c3 = (i3c % 520) >> 2, h3 = i3c & 3;
    dof0 = (r0 * 130 + c0) * RS + h0 * 8;
    dof1 = (r1 * 130 + c1) * RS + h1 * 8;
    dof2 = (r2 * 130 + c2) * RS + h2 * 8;
    dof3 = (r3 * 130 + c3) * RS + h3 * 8;
    sp0 = Xb + ((size_t)(y + r0) * 130 + c0) * 256 + h0 * 8;
    sp1 = Xb + ((size_t)(y + r1) * 130 + c1) * 256 + h1 * 8;
    sp2 = Xb + ((size_t)(y + r2) * 130 + c2) * 256 + h2 * 8;
    sp3 = Xb + ((size_t)(y + r3) * 130 + c3) * 256 + h3 * 8;
  }

  f32x4 acc[4][8];
#pragma unroll
  for (int mt = 0; mt < 4; ++mt)
#pragma unroll
    for (int nt = 0; nt < 8; ++nt) {
      f32x4 z = {0.f, 0.f, 0.f, 0.f};
      acc[mt][nt] = z;
    }

  // B base for this thread: Wb[tap][co_w+lr][c8*32 + lg*8], tap/nt strides const
  const unsigned short* wbase = Wb + (size_t)(co_w + lr) * 256 + lg * 8;

  // prologue: stage ci-chunk 0 into buffer 0; prefetch bf for (c8=0, tap=0)
  {
    const short8 a = *(const short8*)sp0;
    const short8 bq = *(const short8*)sp1;
    const short8 cq = *(const short8*)sp2;
    short8 dq;
    if (sv3) dq = *(const short8*)sp3;
    *(short8*)(Asw + dof0) = a;
    *(short8*)(Asw + dof1) = bq;
    *(short8*)(Asw + dof2) = cq;
    if (sv3) *(short8*)(Asw + dof3) = dq;
  }
  short8 bfb[2][8];
#pragma unroll
  for (int nt = 0; nt < 8; ++nt)
    bfb[0][nt] = *(const short8*)(wbase + (size_t)nt * (16 * 256));
  __syncthreads();

  // Chunk body: phase P (0/1) fixes which bfb half tap0 reads; taps alternate.
  // tap t reads bfb[(t+P)&1]; tap t prefetches (t+1) into bfb[(t+1+P)&1];
  // tap 8 prefetches next chunk's tap0 into bfb[(P+1)&1] (= next phase's tap0).
#define CONV3_CHUNK(C8, P)                                                     \
  {                                                                            \
    const int c8_ = (C8);                                                      \
    short8 n0, n1, n2, n3;                                                     \
    const bool pf_ = c8_ < 7;                                                  \
    if (pf_) {                                                                 \
      const int cn_ = (c8_ + 1) * 32;                                          \
      n0 = *(const short8*)(sp0 + cn_);                                        \
      n1 = *(const short8*)(sp1 + cn_);                                        \
      n2 = *(const short8*)(sp2 + cn_);                                        \
      if (sv3) n3 = *(const short8*)(sp3 + cn_);                               \
    }                                                                          \
    const unsigned short* Ab_ = Asw + ((P)) * BUFN;                            \
    const unsigned short* wchunk_ = wbase + c8_ * 32;                          \
    _Pragma("unroll")                                                          \
    for (int tap = 0; tap < 9; ++tap) {                                        \
      if (tap < 8) {                                                           \
        const unsigned short* wn_ = wchunk_ + (size_t)(tap + 1) * (512 * 256); \
        _Pragma("unroll")                                                      \
        for (int nt = 0; nt < 8; ++nt)                                         \
          bfb[(tap + 1 + (P)) & 1][nt] =                                       \
              *(const short8*)(wn_ + (size_t)nt * (16 * 256));                 \
      } else if (pf_) {                                                        \
        const unsigned short* wn_ = wbase + (c8_ + 1) * 32;                    \
        _Pragma("unroll")                                                      \
        for (int nt = 0; nt < 8; ++nt)                                         \
          bfb[((P) + 1) & 1][nt] =                                             \
              *(const short8*)(wn_ + (size_t)nt * (16 * 256));                 \
      }                                                                        \
      const int ky_ = tap / 3, kx_ = tap % 3;                                  \
      short8 af[4];                                                            \
      _Pragma("unroll")                                                        \
      for (int mt = 0; mt < 4; ++mt) {                                         \
        const int col_ = wm * 64 + mt * 16 + lr + kx_;                         \
        af[mt] = *(const short8*)(Ab_ + (ky_ * 130 + col_) * RS + lg * 8);     \
      }                                                                        \
      _Pragma("unroll")                                                        \
      for (int nt = 0; nt < 8; ++nt) {                                         \
        const short8 bfv = bfb[(tap + (P)) & 1][nt];                           \
        _Pragma("unroll")                                                      \
        for (int mt = 0; mt < 4; ++mt)                                         \
          acc[mt][nt] = __builtin_amdgcn_mfma_f32_16x16x32_bf16(               \
              af[mt], bfv, acc[mt][nt], 0, 0, 0);                              \
      }                                                                        \
    }                                                                          \
    if (pf_) {                                                                 \
      unsigned short* Db_ = Asw + (1 - (P)) * BUFN;                            \
      *(short8*)(Db_ + dof0) = n0;                                             \
      *(short8*)(Db_ + dof1) = n1;                                             \
      *(short8*)(Db_ + dof2) = n2;                                             \
      if (sv3) *(short8*)(Db_ + dof3) = n3;                                    \
    }                                                                          \
    __syncthreads();                                                           \
  }

  for (int it = 0; it < 4; ++it) {
    const int cc = it * 2;
    CONV3_CHUNK(cc, 0)
    CONV3_CHUNK(cc + 1, 1)
  }
#undef CONV3_CHUNK

  // epilogue: bias + tanh + pool by label into LDS
  const int* labp = labels + b * 16384 + y * 128;
  float bco[8];
#pragma unroll
  for (int nt = 0; nt < 8; ++nt) bco[nt] = bias[co_w + nt * 16 + lr];
#pragma unroll
  for (int mt = 0; mt < 4; ++mt) {
#pragma unroll
    for (int r = 0; r < 4; ++r) {
      const int lab = labp[wm * 64 + mt * 16 + lg * 4 + r];
#pragma unroll
      for (int nt = 0; nt < 8; ++nt) {
        const float v = tanh_fast(acc[mt][nt][r] + bco[nt]);
        atomicAdd(&lsum[lab * 512 + co_w + nt * 16 + lr], v);
      }
    }
  }
  __syncthreads();
  for (int i = t; i < 19 * 512; i += 512) {
    const float v = lsum[i];
    if (v != 0.f) {
      const int sI = i >> 9, c = i & 511;
      atomicAdd(&sums[((size_t)b * 19 + sI) * 512 + c], v);
    }
  }
}

// ---------------- finalize: out = cnt>0 ? sums/max(cnt,1) : 0 ----------------
__global__ __launch_bounds__(256) void finalize_kernel(
    const float* __restrict__ sums, const float* __restrict__ cnt,
    float* __restrict__ out) {
  const int i = blockIdx.x * 256 + threadIdx.x;
  if (i >= B * 19 * 512) return;
  const int bs = i >> 9;
  const float c = cnt[bs];
  out[i] = c > 0.f ? sums[i] / fmaxf(c, 1.f) : 0.f;
}

// ---------------------------------------------------------------------------
extern "C" void kernel_launch(void* const* d_in, const int* in_sizes, int n_in,
                              void* d_out, int out_size, void* d_ws,
                              size_t ws_size, hipStream_t stream) {
  const float* input = (const float*)d_in[0];
  const float* segmap = (const float*)d_in[1];
  const float* w0 = (const float*)d_in[2];
  const float* b0 = (const float*)d_in[3];
  const float* w1 = (const float*)d_in[4];
  const float* b1 = (const float*)d_in[5];
  const float* w2 = (const float*)d_in[6];
  const float* b2 = (const float*)d_in[7];
  const float* wt = (const float*)d_in[8];
  const float* bt = (const float*)d_in[9];
  const float* w3 = (const float*)d_in[10];
  const float* b3 = (const float*)d_in[11];
  float* out = (float*)d_out;

  float* ws = (float*)d_ws;
  float* x0 = ws;                                    // 16,777,216 f
  float* x1 = x0 + 16777216;                         //  8,388,608 f
  float* x2 = x1 + 8388608;                          //  4,194,304 f
  unsigned short* X2p = (unsigned short*)(x2 + 4194304);  // 4,326,400 us
  unsigned short* Y = X2p + 4326400;                 // 33,554,432 us
  float* sums = (float*)(Y + 33554432);              //     77,824 f
  float* cnt = sums + 77824;                         //        152 f
  float* ssum = cnt + 152;                           //      2,048 f
  float* ssq = ssum + 2048;                          //      2,048 f
  int* labels = (int*)(ssq + 2048);                  //    131,072 i
  unsigned short* Wb = (unsigned short*)(labels + 131072);  // 1,179,648 us
  unsigned short* Wtb = Wb + 1179648;                //    294,912 us
  unsigned short* Xpad = (unsigned short*)ws;        // 69.2MB over x0+x1 (dead)

  hipMemsetAsync(sums, 0, (77824 + 152 + 2048 + 2048) * sizeof(float), stream);

  wprep_kernel<<<dim3((9 * 512 * 256 + 255) / 256), 256, 0, stream>>>(w3, Wb);
  wtprep_kernel<<<dim3((9 * 256 * 128 + 255) / 256), 256, 0, stream>>>(wt, Wtb);
  conv0_kernel<<<dim3(256, B), 256, 0, stream>>>(input, w0, b0, x0);
  inorm_lrelu_kernel<<<dim3(B * 32), 256, 0, stream>>>(x0, 65536);
  conv_s2_kernel<32, 64, 256><<<dim3(64, 2, B), 256, 0, stream>>>(x0, w1, b1, x1);
  inorm_lrelu_kernel<<<dim3(B * 64), 256, 0, stream>>>(x1, 16384);
  conv_s2_kernel<64, 128, 128><<<dim3(16, 4, B), 256, 0, stream>>>(x1, w2, b2, x2);
  inorm_lrelu_kernel<<<dim3(B * 128), 256, 0, stream>>>(x2, 4096);
  transpose_x2_kernel<<<dim3(128, B), 256, 0, stream>>>(x2, X2p);
  zpad_x2_kernel<<<dim3(B), 256, 0, stream>>>(X2p);
  convt_mfma_kernel<<<dim3(2048), 256, 0, stream>>>(X2p, Wtb, bt, Y);
  inorm_stats_kernel<<<dim3(16, B), 256, 0, stream>>>(Y, ssum, ssq);
  inorm_apply_kernel<<<dim3(16, B), 256, 0, stream>>>(Y, ssum, ssq, Xpad);
  pad_rows_kernel<<<dim3(2 * B), 256, 0, stream>>>(Xpad);
  pad_cols_kernel<<<dim3(2 * B), 256, 0, stream>>>(Xpad);
  label_kernel<<<dim3(64, B), 256, 0, stream>>>(segmap, labels, cnt);
  conv3_mfma_pool_kernel<<<dim3(1024), 512, 0, stream>>>(Xpad, Wb, b3, labels, sums);
  finalize_kernel<<<dim3((B * 19 * 512 + 255) / 256), 256, 0, stream>>>(sums, cnt, out);
}

// Round 8
// 1398.483 us; speedup vs baseline: 1.4569x; 1.4569x over previous
//
#include <hip/hip_runtime.h>

// ---------------------------------------------------------------------------
// SPADE-style encoder.
// conv3: bf16 MFMA implicit-GEMM, block = 1 image row (128 px) x 512 co,
//        8 waves, wave tile 64x128. R8: (a) B (weights) repacked into
//        MFMA-fragment-ordered tiles -> each wave B-load is one coalesced
//        1KB burst (R6 had 16-way fragmented loads); (b) lsum unioned with
//        the staging LDS (epilogue-only) -> 56KB/block -> 2 blocks/CU.
// convT: bf16 MFMA per-parity-class GEMM with the same coalesced B tiles.
// conv0/conv1/conv2 + their instance-norms still fp32 vector.
// ---------------------------------------------------------------------------

#define B 8

typedef __attribute__((ext_vector_type(8))) short short8;
typedef __attribute__((ext_vector_type(4))) float f32x4;

static __device__ __forceinline__ unsigned short f2bf(float f) {
  union { float f; unsigned u; } v;
  v.f = f;
  unsigned r = v.u + 0x7fffu + ((v.u >> 16) & 1u);
  return (unsigned short)(r >> 16);
}
static __device__ __forceinline__ float bf2f(unsigned short h) {
  union { unsigned u; float f; } v;
  v.u = (unsigned)h << 16;
  return v.f;
}
static __device__ __forceinline__ float tanh_fast(float x) {
  float ax = fabsf(x);
  ax = fminf(ax, 20.f);
  const float e = __expf(-2.f * ax);
  const float t = (1.f - e) / (1.f + e);
  return __builtin_copysignf(t, x);
}

// ---------------- conv0: 3->32, reflect pad 1, 256x256 ----------------
__global__ __launch_bounds__(256) void conv0_kernel(
    const float* __restrict__ in, const float* __restrict__ w,
    const float* __restrict__ bias, float* __restrict__ out) {
  __shared__ float sw[32 * 27 + 32];
  for (int i = threadIdx.x; i < 32 * 27; i += 256) sw[i] = w[i];
  if (threadIdx.x < 32) sw[32 * 27 + threadIdx.x] = bias[threadIdx.x];
  __syncthreads();
  const int b = blockIdx.y;
  const int p = blockIdx.x * 256 + threadIdx.x;
  const int y = p >> 8, x = p & 255;
  const float* inb = in + (size_t)b * 3 * 65536;
  float v[27];
#pragma unroll
  for (int c = 0; c < 3; ++c) {
#pragma unroll
    for (int ky = 0; ky < 3; ++ky) {
      int iy = y + ky - 1;
      iy = iy < 0 ? -iy : (iy > 255 ? 510 - iy : iy);
#pragma unroll
      for (int kx = 0; kx < 3; ++kx) {
        int ix = x + kx - 1;
        ix = ix < 0 ? -ix : (ix > 255 ? 510 - ix : ix);
        v[c * 9 + ky * 3 + kx] = inb[c * 65536 + iy * 256 + ix];
      }
    }
  }
  float* ob = out + (size_t)b * 32 * 65536 + p;
#pragma unroll
  for (int co = 0; co < 32; ++co) {
    float a = sw[32 * 27 + co];
#pragma unroll
    for (int k = 0; k < 27; ++k) a = fmaf(v[k], sw[co * 27 + k], a);
    ob[(size_t)co * 65536] = a;
  }
}

// ---------------- fused instance-norm + leaky relu (in place, fp32) ----------
__global__ __launch_bounds__(256) void inorm_lrelu_kernel(float* __restrict__ x,
                                                          int HW) {
  const size_t base = (size_t)blockIdx.x * HW;
  float4* p = (float4*)(x + base);
  const int n4 = HW >> 2;
  float s = 0.f, q = 0.f;
  for (int i = threadIdx.x; i < n4; i += 256) {
    float4 v = p[i];
    s += (v.x + v.y) + (v.z + v.w);
    q += (v.x * v.x + v.y * v.y) + (v.z * v.z + v.w * v.w);
  }
  __shared__ float rs[256], rq[256];
  rs[threadIdx.x] = s;
  rq[threadIdx.x] = q;
  __syncthreads();
  for (int st = 128; st > 0; st >>= 1) {
    if (threadIdx.x < st) {
      rs[threadIdx.x] += rs[threadIdx.x + st];
      rq[threadIdx.x] += rq[threadIdx.x + st];
    }
    __syncthreads();
  }
  const float m = rs[0] / (float)HW;
  float var = rq[0] / (float)HW - m * m;
  var = var < 0.f ? 0.f : var;
  const float r = rsqrtf(var + 1e-5f);
  for (int i = threadIdx.x; i < n4; i += 256) {
    float4 v = p[i];
    v.x = (v.x - m) * r; v.x = v.x >= 0.f ? v.x : 0.2f * v.x;
    v.y = (v.y - m) * r; v.y = v.y >= 0.f ? v.y : 0.2f * v.y;
    v.z = (v.z - m) * r; v.z = v.z >= 0.f ? v.z : 0.2f * v.z;
    v.w = (v.w - m) * r; v.w = v.w >= 0.f ? v.w : 0.2f * v.w;
    p[i] = v;
  }
}

// ---------------- 3x3 stride-2 zero-pad-1 conv, 32 co per block ----------------
template <int CIN, int COUT, int HIN>
__global__ __launch_bounds__(256) void conv_s2_kernel(
    const float* __restrict__ in, const float* __restrict__ w,
    const float* __restrict__ bias, float* __restrict__ out) {
  constexpr int HOUT = HIN / 2;
  const int b = blockIdx.z;
  const int co0 = blockIdx.y * 32;
  const int p = blockIdx.x * 256 + threadIdx.x;
  const int oy = p / HOUT, ox = p % HOUT;
  float acc[32];
#pragma unroll
  for (int i = 0; i < 32; ++i) acc[i] = bias[co0 + i];
  const float* inb = in + (size_t)b * CIN * HIN * HIN;
  const int iy0 = 2 * oy - 1, ix0 = 2 * ox - 1;
  for (int ci = 0; ci < CIN; ++ci) {
    float v[9];
    const float* ip = inb + (size_t)ci * HIN * HIN;
#pragma unroll
    for (int ky = 0; ky < 3; ++ky) {
      const int iy = iy0 + ky;
      const bool yok = (unsigned)iy < (unsigned)HIN;
#pragma unroll
      for (int kx = 0; kx < 3; ++kx) {
        const int ix = ix0 + kx;
        const bool ok = yok && ((unsigned)ix < (unsigned)HIN);
        v[ky * 3 + kx] = ok ? ip[iy * HIN + ix] : 0.f;
      }
    }
    const float* wp = w + ((size_t)co0 * CIN + ci) * 9;
#pragma unroll
    for (int co = 0; co < 32; ++co) {
#pragma unroll
      for (int k = 0; k < 9; ++k)
        acc[co] = fmaf(v[k], wp[(size_t)co * CIN * 9 + k], acc[co]);
    }
  }
  float* ob = out + ((size_t)b * COUT + co0) * HOUT * HOUT + p;
#pragma unroll
  for (int co = 0; co < 32; ++co) ob[(size_t)co * HOUT * HOUT] = acc[co];
}

// -------- transpose x2: fp32 [b][128][4096] -> X2p bf16 [b][65][65][128] ----
__global__ __launch_bounds__(256) void transpose_x2_kernel(
    const float* __restrict__ x2, unsigned short* __restrict__ X2p) {
  const int b = blockIdx.y;
  const int p0 = (blockIdx.x & 63) * 64;
  const int ci0 = (blockIdx.x >> 6) * 64;
  __shared__ unsigned short T[64][66];
  const float* src = x2 + (size_t)b * 128 * 4096;
  const int t = threadIdx.x;
#pragma unroll
  for (int r = 0; r < 16; ++r) {
    const int ci_l = r * 4 + (t >> 6);
    const int p_l = t & 63;
    T[ci_l][p_l] = f2bf(src[(size_t)(ci0 + ci_l) * 4096 + p0 + p_l]);
  }
  __syncthreads();
  unsigned short* dst = X2p + (size_t)b * 65 * 65 * 128;
#pragma unroll
  for (int r = 0; r < 2; ++r) {
    const int p_l = r * 32 + (t >> 3);
    const int c0 = (t & 7) * 8;
    union { short8 v; unsigned short u[8]; } pk;
#pragma unroll
    for (int j = 0; j < 8; ++j) pk.u[j] = T[c0 + j][p_l];
    const int p = p0 + p_l;
    const int yy = p >> 6, xx = p & 63;
    *(short8*)(dst + ((size_t)yy * 65 + xx) * 128 + ci0 + c0) = pk.v;
  }
}

// ---------------- zero pad row 64 / col 64 of X2p ----------------
__global__ __launch_bounds__(256) void zpad_x2_kernel(unsigned short* __restrict__ X2p) {
  const int b = blockIdx.x;
  unsigned short* Xb = X2p + (size_t)b * 65 * 65 * 128;
  for (int i = threadIdx.x; i < 129 * 128; i += 256) {
    const int j = i >> 7, ci = i & 127;
    size_t off;
    if (j < 65) off = ((size_t)64 * 65 + j) * 128 + ci;
    else off = ((size_t)(j - 65) * 65 + 64) * 128 + ci;
    Xb[off] = 0;
  }
}

// -------- weight repack (coalesced tiles): wt fp32 [256][128][3][3] ->
// -------- Wtb2 bf16 [9][cot16][c4(4)][lane64][8]; lane=(lg<<4)|lr:
// -------- co = cot*16+lr, ci = c4*32 + lg*8 + e ----------------------------
__global__ __launch_bounds__(256) void wtprep_kernel(const float* __restrict__ wt,
                                                     unsigned short* __restrict__ Wtb2) {
  const int i = blockIdx.x * 256 + threadIdx.x;
  if (i >= 9 * 256 * 128) return;
  const int e = i & 7, lane = (i >> 3) & 63, c4 = (i >> 9) & 3;
  const int cot = (i >> 11) & 15, tap = i >> 15;
  const int co = cot * 16 + (lane & 15);
  const int ci = c4 * 32 + (lane >> 4) * 8 + e;
  Wtb2[i] = f2bf(wt[((size_t)co * 128 + ci) * 9 + tap]);
}

// ---------------- convT as bf16 MFMA per-parity-class GEMM ----------------
__global__ __launch_bounds__(256, 3) void convt_mfma_kernel(
    const unsigned short* __restrict__ X2p, const unsigned short* __restrict__ Wtb2,
    const float* __restrict__ bt, unsigned short* __restrict__ Y) {
  const int raw = blockIdx.x;
  const int swz = (raw & 7) * 256 + (raw >> 3);
  const int b = swz >> 8;
  const int rem = swz & 255;
  const int cls = rem >> 6;
  const int sy = rem & 63;
  const int py = cls & 1, px = cls >> 1;

  const int kyA = py ? 0 : 1, kxA = px ? 0 : 1;
  int tk[4], tdy[4], tdx[4];
  int ntaps = 0;
  tk[ntaps] = kyA * 3 + kxA; tdy[ntaps] = 0; tdx[ntaps] = 0; ++ntaps;
  if (px) { tk[ntaps] = kyA * 3 + 2; tdy[ntaps] = 0; tdx[ntaps] = 1; ++ntaps; }
  if (py) { tk[ntaps] = 6 + kxA; tdy[ntaps] = 1; tdx[ntaps] = 0; ++ntaps; }
  if (py && px) { tk[ntaps] = 8; tdy[ntaps] = 1; tdx[ntaps] = 1; ++ntaps; }

  constexpr int CS = 36;
  constexpr int BUFN = 2 * 65 * CS;
  __shared__ unsigned short As2[2 * BUFN];

  const int t = threadIdx.x;
  const int lane = t & 63;
  const int wn = t >> 6;
  const int lg = lane >> 4, lr = lane & 15;
  const int co_w = wn * 64;

  const unsigned short* Xb = X2p + (size_t)b * 65 * 65 * 128;

  int dof0, dof1, dof2;
  const unsigned short *sp0, *sp1, *sp2;
  bool sv2;
  {
    const int i0 = t, i1 = t + 256, i2 = t + 512;
    const int r0 = i0 / 260, c0_ = (i0 % 260) >> 2, h0 = i0 & 3;
    const int r1 = i1 / 260, c1_ = (i1 % 260) >> 2, h1 = i1 & 3;
    sv2 = i2 < 520;
    const int i2c = sv2 ? i2 : 512;
    const int r2 = i2c / 260, c2_ = (i2c % 260) >> 2, h2 = i2c & 3;
    dof0 = (r0 * 65 + c0_) * CS + h0 * 8;
    dof1 = (r1 * 65 + c1_) * CS + h1 * 8;
    dof2 = (r2 * 65 + c2_) * CS + h2 * 8;
    sp0 = Xb + ((size_t)(sy + r0) * 65 + c0_) * 128 + h0 * 8;
    sp1 = Xb + ((size_t)(sy + r1) * 65 + c1_) * 128 + h1 * 8;
    sp2 = Xb + ((size_t)(sy + r2) * 65 + c2_) * 128 + h2 * 8;
  }

  f32x4 acc[4][4];
#pragma unroll
  for (int mt = 0; mt < 4; ++mt)
#pragma unroll
    for (int nt = 0; nt < 4; ++nt) {
      f32x4 z = {0.f, 0.f, 0.f, 0.f};
      acc[mt][nt] = z;
    }

  {
    const short8 a = *(const short8*)sp0;
    const short8 bq = *(const short8*)sp1;
    short8 cq;
    if (sv2) cq = *(const short8*)sp2;
    *(short8*)(As2 + dof0) = a;
    *(short8*)(As2 + dof1) = bq;
    if (sv2) *(short8*)(As2 + dof2) = cq;
  }
  __syncthreads();

  // coalesced B base: tile index (tap*16 + cot)*4 + c8, elements lane*8
  const unsigned short* wlane = Wtb2 + (size_t)lane * 8;

  for (int c8 = 0; c8 < 4; ++c8) {
    short8 n0, n1, n2;
    if (c8 < 3) {
      const int cn = (c8 + 1) * 32;
      n0 = *(const short8*)(sp0 + cn);
      n1 = *(const short8*)(sp1 + cn);
      if (sv2) n2 = *(const short8*)(sp2 + cn);
    }
    const unsigned short* Ab = As2 + (c8 & 1) * BUFN;
    for (int tp = 0; tp < ntaps; ++tp) {
      const int dy = tdy[tp], dx = tdx[tp];
      short8 af[4];
#pragma unroll
      for (int mt = 0; mt < 4; ++mt)
        af[mt] = *(const short8*)(Ab + (dy * 65 + mt * 16 + lr + dx) * CS + lg * 8);
      const unsigned short* wt_ =
          wlane + (size_t)(((tk[tp] * 16 + wn * 4) * 4) + c8) * 512;
#pragma unroll
      for (int nt = 0; nt < 4; ++nt) {
        const short8 bf = *(const short8*)(wt_ + (size_t)nt * (4 * 512));
#pragma unroll
        for (int mt = 0; mt < 4; ++mt)
          acc[mt][nt] = __builtin_amdgcn_mfma_f32_16x16x32_bf16(
              af[mt], bf, acc[mt][nt], 0, 0, 0);
      }
    }
    if (c8 < 3) {
      unsigned short* Db = As2 + ((c8 + 1) & 1) * BUFN;
      *(short8*)(Db + dof0) = n0;
      *(short8*)(Db + dof1) = n1;
      if (sv2) *(short8*)(Db + dof2) = n2;
    }
    __syncthreads();
  }

  const int oy = 2 * sy + py;
  unsigned short* Yb = Y + ((size_t)b * 16384 + (size_t)oy * 128 + px) * 256;
  float bco[4];
#pragma unroll
  for (int nt = 0; nt < 4; ++nt) bco[nt] = bt[co_w + nt * 16 + lr];
#pragma unroll
  for (int mt = 0; mt < 4; ++mt) {
#pragma unroll
    for (int r = 0; r < 4; ++r) {
      const int sx = mt * 16 + lg * 4 + r;
      unsigned short* yp = Yb + (size_t)(2 * sx) * 256 + co_w + lr;
#pragma unroll
      for (int nt = 0; nt < 4; ++nt)
        yp[nt * 16] = f2bf(acc[mt][nt][r] + bco[nt]);
    }
  }
}

// ---------------- instance-norm stats over pixel-major Y ----------------
__global__ __launch_bounds__(256) void inorm_stats_kernel(
    const unsigned short* __restrict__ Y, float* __restrict__ ssum,
    float* __restrict__ ssq) {
  const int b = blockIdx.y, sl = blockIdx.x, c = threadIdx.x;
  const unsigned short* p = Y + ((size_t)b * 16384 + (size_t)sl * 1024) * 256 + c;
  float s = 0.f, q = 0.f;
  for (int i = 0; i < 1024; ++i) {
    const float v = bf2f(p[(size_t)i * 256]);
    s += v;
    q += v * v;
  }
  atomicAdd(&ssum[b * 256 + c], s);
  atomicAdd(&ssq[b * 256 + c], q);
}

// ------- apply IN + LReLU to Y, write bf16 into Xpad interior -------
__global__ __launch_bounds__(256) void inorm_apply_kernel(
    const unsigned short* __restrict__ Y, const float* __restrict__ ssum,
    const float* __restrict__ ssq, unsigned short* __restrict__ Xpad) {
  const int b = blockIdx.y, sl = blockIdx.x, c = threadIdx.x;
  const float m = ssum[b * 256 + c] * (1.f / 16384.f);
  float var = ssq[b * 256 + c] * (1.f / 16384.f) - m * m;
  var = var < 0.f ? 0.f : var;
  const float r = rsqrtf(var + 1e-5f);
  const unsigned short* p = Y + ((size_t)b * 16384 + (size_t)sl * 1024) * 256 + c;
  unsigned short* dst = Xpad + (size_t)b * 130 * 130 * 256 + c;
  for (int i = 0; i < 1024; ++i) {
    const int pix = sl * 1024 + i;
    const int yy = pix >> 7, xx = pix & 127;
    float v = bf2f(p[(size_t)i * 256]);
    v = (v - m) * r;
    v = v >= 0.f ? v : 0.2f * v;
    dst[((size_t)(yy + 1) * 130 + (xx + 1)) * 256] = f2bf(v);
  }
}

// ---------------- reflect borders of Xpad: rows then cols ----------------
__global__ __launch_bounds__(256) void pad_rows_kernel(unsigned short* __restrict__ Xp) {
  const int b = blockIdx.x >> 1, side = blockIdx.x & 1;
  unsigned short* Xb = Xp + (size_t)b * 130 * 130 * 256;
  const int dr = side ? 129 : 0, sr = side ? 127 : 2;
  for (int i = threadIdx.x; i < 4096; i += 256) {
    const int c = 1 + (i >> 5), o = (i & 31) * 8;
    *(short8*)(Xb + ((size_t)dr * 130 + c) * 256 + o) =
        *(const short8*)(Xb + ((size_t)sr * 130 + c) * 256 + o);
  }
}
__global__ __launch_bounds__(256) void pad_cols_kernel(unsigned short* __restrict__ Xp) {
  const int b = blockIdx.x >> 1, side = blockIdx.x & 1;
  unsigned short* Xb = Xp + (size_t)b * 130 * 130 * 256;
  const int dc = side ? 129 : 0, sc = side ? 127 : 2;
  for (int i = threadIdx.x; i < 130 * 32; i += 256) {
    const int r = i >> 5, o = (i & 31) * 8;
    *(short8*)(Xb + ((size_t)r * 130 + dc) * 256 + o) =
        *(const short8*)(Xb + ((size_t)r * 130 + sc) * 256 + o);
  }
}

// ------ weight repack (coalesced tiles): w3 fp32 [512][256][9] ->
// ------ Wb2 bf16 [9][cot32][c8(8)][lane64][8]; co=cot*16+lr, ci=c8*32+lg*8+e
__global__ __launch_bounds__(256) void wprep_kernel(const float* __restrict__ w3,
                                                    unsigned short* __restrict__ Wb2) {
  const int i = blockIdx.x * 256 + threadIdx.x;
  if (i >= 9 * 512 * 256) return;
  const int e = i & 7, lane = (i >> 3) & 63, c8 = (i >> 9) & 7;
  const int cot = (i >> 12) & 31, tap = i >> 17;
  const int co = cot * 16 + (lane & 15);
  const int ci = c8 * 32 + (lane >> 4) * 8 + e;
  Wb2[i] = f2bf(w3[((size_t)co * 256 + ci) * 9 + tap]);
}

// ---------------- label extraction + counts from one-hot segmap ----------------
__global__ __launch_bounds__(256) void label_kernel(
    const float* __restrict__ segmap, int* __restrict__ labels,
    float* __restrict__ cnt) {
  const int b = blockIdx.y;
  const int p = blockIdx.x * 256 + threadIdx.x;
  const int i = p >> 7, j = p & 127;
  const float* sp = segmap + (size_t)b * 19 * 65536 + (2 * i) * 256 + 2 * j;
  int lab = 0;
#pragma unroll
  for (int s = 0; s < 19; ++s)
    if (sp[(size_t)s * 65536] != 0.f) lab = s;
  labels[b * 16384 + p] = lab;
  atomicAdd(&cnt[b * 19 + lab], 1.0f);
}

// ---------------- conv3: bf16 MFMA implicit GEMM + tanh + region pool --------
// Block = 512 threads (8 waves) = one image row (128 px) x ALL 512 co.
// Wave grid 2Mx4N, wave tile 64px x 128co, acc 4x8 f32x4 = 128 AGPR.
// Per 32-ci chunk: stage 3x130 halo window once (serves all 9 taps).
// R8: coalesced Wb2 tiles (1 burst per B-fragment); lsum UNIONED with the
// staging buffers (epilogue-only) -> LDS 56KB -> 2 blocks/CU (4 waves/SIMD).
__global__ __launch_bounds__(512, 2) void conv3_mfma_pool_kernel(
    const unsigned short* __restrict__ Xpad, const unsigned short* __restrict__ Wb2,
    const float* __restrict__ bias, const int* __restrict__ labels,
    float* __restrict__ sums) {
  // XCD swizzle: 1024 = 8 XCDs x 128 -> one batch per XCD
  const int raw = blockIdx.x;
  const int swz = (raw & 7) * 128 + (raw >> 3);
  const int b = swz >> 7;
  const int y = swz & 127;

  constexpr int RS = 36;              // LDS col-entry stride (72B)
  constexpr int BUFN = 3 * 130 * RS;  // 14040 ushort per buffer
  __shared__ unsigned short Asw[2 * BUFN];  // 56.2 KB; reused as lsum in epilogue
  float* lsum = (float*)Asw;                // 19*512*4 = 38.9 KB <= 56.2 KB

  const int t = threadIdx.x;
  const int lane = t & 63;
  const int wave = t >> 6;     // 0..7
  const int wm = wave >> 2;    // 0..1: M group (64 px)
  const int wn = wave & 3;     // 0..3: N group (128 co)
  const int lg = lane >> 4, lr = lane & 15;
  const int co_w = wn * 128;

  const unsigned short* Xb = Xpad + (size_t)b * 130 * 130 * 256;

  // staging: 1560 chunks = r(3) x c(130) x h(4)
  int dof0, dof1, dof2, dof3;
  const unsigned short *sp0, *sp1, *sp2, *sp3;
  bool sv3;
  {
    const int i0 = t, i1 = t + 512, i2 = t + 1024, i3 = t + 1536;
    const int r0 = i0 / 520, c0 = (i0 % 520) >> 2, h0 = i0 & 3;
    const int r1 = i1 / 520, c1 = (i1 % 520) >> 2, h1 = i1 & 3;
    const int r2 = i2 / 520, c2 = (i2 % 520) >> 2, h2 = i2 & 3;
    sv3 = i3 < 1560;
    const int i3c = sv3 ? i3 : 1536;
    const int r3 = i3c / 520, c3 = (i3c % 520) >> 2, h3 = i3c & 3;
    dof0 = (r0 * 130 + c0) * RS + h0 * 8;
    dof1 = (r1 * 130 + c1) * RS + h1 * 8;
    dof2 = (r2 * 130 + c2) * RS + h2 * 8;
    dof3 = (r3 * 130 + c3) * RS + h3 * 8;
    sp0 = Xb + ((size_t)(y + r0) * 130 + c0) * 256 + h0 * 8;
    sp1 = Xb + ((size_t)(y + r1) * 130 + c1) * 256 + h1 * 8;
    sp2 = Xb + ((size_t)(y + r2) * 130 + c2) * 256 + h2 * 8;
    sp3 = Xb + ((size_t)(y + r3) * 130 + c3) * 256 + h3 * 8;
  }

  f32x4 acc[4][8];
#pragma unroll
  for (int mt = 0; mt < 4; ++mt)
#pragma unroll
    for (int nt = 0; nt < 8; ++nt) {
      f32x4 z = {0.f, 0.f, 0.f, 0.f};
      acc[mt][nt] = z;
    }

  // coalesced B base: tile index (tap*32 + wn*8 + nt)*8 + c8, elements lane*8
  const unsigned short* wlane = Wb2 + (size_t)lane * 8;

  // prologue: stage ci-chunk 0 into buffer 0
  {
    const short8 a = *(const short8*)sp0;
    const short8 bq = *(const short8*)sp1;
    const short8 cq = *(const short8*)sp2;
    short8 dq;
    if (sv3) dq = *(const short8*)sp3;
    *(short8*)(Asw + dof0) = a;
    *(short8*)(Asw + dof1) = bq;
    *(short8*)(Asw + dof2) = cq;
    if (sv3) *(short8*)(Asw + dof3) = dq;
  }
  __syncthreads();

  for (int c8 = 0; c8 < 8; ++c8) {
    short8 n0, n1, n2, n3;
    if (c8 < 7) {
      const int cn = (c8 + 1) * 32;
      n0 = *(const short8*)(sp0 + cn);
      n1 = *(const short8*)(sp1 + cn);
      n2 = *(const short8*)(sp2 + cn);
      if (sv3) n3 = *(const short8*)(sp3 + cn);
    }
    const unsigned short* Ab = Asw + (c8 & 1) * BUFN;
#pragma unroll
    for (int ky = 0; ky < 3; ++ky) {
#pragma unroll
      for (int kx = 0; kx < 3; ++kx) {
        short8 af[4];
#pragma unroll
        for (int mt = 0; mt < 4; ++mt) {
          const int col = wm * 64 + mt * 16 + lr + kx;
          af[mt] = *(const short8*)(Ab + (ky * 130 + col) * RS + lg * 8);
        }
        const unsigned short* wt_ =
            wlane + (size_t)(((ky * 3 + kx) * 32 + wn * 8) * 8 + c8) * 512;
#pragma unroll
        for (int nt = 0; nt < 8; ++nt) {
          const short8 bf = *(const short8*)(wt_ + (size_t)nt * (8 * 512));
#pragma unroll
          for (int mt = 0; mt < 4; ++mt)
            acc[mt][nt] = __builtin_amdgcn_mfma_f32_16x16x32_bf16(
                af[mt], bf, acc[mt][nt], 0, 0, 0);
        }
      }
    }
    if (c8 < 7) {
      unsigned short* Db = Asw + ((c8 + 1) & 1) * BUFN;
      *(short8*)(Db + dof0) = n0;
      *(short8*)(Db + dof1) = n1;
      *(short8*)(Db + dof2) = n2;
      if (sv3) *(short8*)(Db + dof3) = n3;
    }
    __syncthreads();
  }

  // epilogue: staging buffers are dead -> zero lsum in the same LDS
  for (int i = t; i < 19 * 512; i += 512) lsum[i] = 0.f;
  __syncthreads();

  const int* labp = labels + b * 16384 + y * 128;
  float bco[8];
#pragma unroll
  for (int nt = 0; nt < 8; ++nt) bco[nt] = bias[co_w + nt * 16 + lr];
#pragma unroll
  for (int mt = 0; mt < 4; ++mt) {
#pragma unroll
    for (int r = 0; r < 4; ++r) {
      const int lab = labp[wm * 64 + mt * 16 + lg * 4 + r];
#pragma unroll
      for (int nt = 0; nt < 8; ++nt) {
        const float v = tanh_fast(acc[mt][nt][r] + bco[nt]);
        atomicAdd(&lsum[lab * 512 + co_w + nt * 16 + lr], v);
      }
    }
  }
  __syncthreads();
  for (int i = t; i < 19 * 512; i += 512) {
    const float v = lsum[i];
    if (v != 0.f) {
      const int sI = i >> 9, c = i & 511;
      atomicAdd(&sums[((size_t)b * 19 + sI) * 512 + c], v);
    }
  }
}

// ---------------- finalize: out = cnt>0 ? sums/max(cnt,1) : 0 ----------------
__global__ __launch_bounds__(256) void finalize_kernel(
    const float* __restrict__ sums, const float* __restrict__ cnt,
    float* __restrict__ out) {
  const int i = blockIdx.x * 256 + threadIdx.x;
  if (i >= B * 19 * 512) return;
  const int bs = i >> 9;
  const float c = cnt[bs];
  out[i] = c > 0.f ? sums[i] / fmaxf(c, 1.f) : 0.f;
}

// ---------------------------------------------------------------------------
extern "C" void kernel_launch(void* const* d_in, const int* in_sizes, int n_in,
                              void* d_out, int out_size, void* d_ws,
                              size_t ws_size, hipStream_t stream) {
  const float* input = (const float*)d_in[0];
  const float* segmap = (const float*)d_in[1];
  const float* w0 = (const float*)d_in[2];
  const float* b0 = (const float*)d_in[3];
  const float* w1 = (const float*)d_in[4];
  const float* b1 = (const float*)d_in[5];
  const float* w2 = (const float*)d_in[6];
  const float* b2 = (const float*)d_in[7];
  const float* wt = (const float*)d_in[8];
  const float* bt = (const float*)d_in[9];
  const float* w3 = (const float*)d_in[10];
  const float* b3 = (const float*)d_in[11];
  float* out = (float*)d_out;

  float* ws = (float*)d_ws;
  float* x0 = ws;                                    // 16,777,216 f
  float* x1 = x0 + 16777216;                         //  8,388,608 f
  float* x2 = x1 + 8388608;                          //  4,194,304 f
  unsigned short* X2p = (unsigned short*)(x2 + 4194304);  // 4,326,400 us
  unsigned short* Y = X2p + 4326400;                 // 33,554,432 us
  float* sums = (float*)(Y + 33554432);              //     77,824 f
  float* cnt = sums + 77824;                         //        152 f
  float* ssum = cnt + 152;                           //      2,048 f
  float* ssq = ssum + 2048;                          //      2,048 f
  int* labels = (int*)(ssq + 2048);                  //    131,072 i
  unsigned short* Wb2 = (unsigned short*)(labels + 131072);  // 1,179,648 us
  unsigned short* Wtb2 = Wb2 + 1179648;              //    294,912 us
  unsigned short* Xpad = (unsigned short*)ws;        // 69.2MB over x0+x1 (dead)

  hipMemsetAsync(sums, 0, (77824 + 152 + 2048 + 2048) * sizeof(float), stream);

  wprep_kernel<<<dim3((9 * 512 * 256 + 255) / 256), 256, 0, stream>>>(w3, Wb2);
  wtprep_kernel<<<dim3((9 * 256 * 128 + 255) / 256), 256, 0, stream>>>(wt, Wtb2);
  conv0_kernel<<<dim3(256, B), 256, 0, stream>>>(input, w0, b0, x0);
  inorm_lrelu_kernel<<<dim3(B * 32), 256, 0, stream>>>(x0, 65536);
  conv_s2_kernel<32, 64, 256><<<dim3(64, 2, B), 256, 0, stream>>>(x0, w1, b1, x1);
  inorm_lrelu_kernel<<<dim3(B * 64), 256, 0, stream>>>(x1, 16384);
  conv_s2_kernel<64, 128, 128><<<dim3(16, 4, B), 256, 0, stream>>>(x1, w2, b2, x2);
  inorm_lrelu_kernel<<<dim3(B * 128), 256, 0, stream>>>(x2, 4096);
  transpose_x2_kernel<<<dim3(128, B), 256, 0, stream>>>(x2, X2p);
  zpad_x2_kernel<<<dim3(B), 256, 0, stream>>>(X2p);
  convt_mfma_kernel<<<dim3(2048), 256, 0, stream>>>(X2p, Wtb2, bt, Y);
  inorm_stats_kernel<<<dim3(16, B), 256, 0, stream>>>(Y, ssum, ssq);
  inorm_apply_kernel<<<dim3(16, B), 256, 0, stream>>>(Y, ssum, ssq, Xpad);
  pad_rows_kernel<<<dim3(2 * B), 256, 0, stream>>>(Xpad);
  pad_cols_kernel<<<dim3(2 * B), 256, 0, stream>>>(Xpad);
  label_kernel<<<dim3(64, B), 256, 0, stream>>>(segmap, labels, cnt);
  conv3_mfma_pool_kernel<<<dim3(1024), 512, 0, stream>>>(Xpad, Wb2, b3, labels, sums);
  finalize_kernel<<<dim3((B * 19 * 512 + 255) / 256), 256, 0, stream>>>(sums, cnt, out);
}

// Round 9
// 1391.040 us; speedup vs baseline: 1.4647x; 1.0054x over previous
//
#include <hip/hip_runtime.h>

// ---------------------------------------------------------------------------
// SPADE-style encoder.
// conv3: bf16 MFMA implicit-GEMM, block = 1 image row (128 px) x 512 co,
//        8 waves, wave tile 64x128. R9: A-halo staged via async
//        global_load_lds (linear LDS + XOR-swizzled source/read pair),
//        freeing ~40 VGPRs so all 8 B-fragments stay in flight per tap
//        (R8 was register-starved -> serialized B round-trips).
// convT: bf16 MFMA per-parity-class GEMM with coalesced B tiles.
// conv0/conv1/conv2 + their instance-norms still fp32 vector.
// ---------------------------------------------------------------------------

#define B 8

typedef __attribute__((ext_vector_type(8))) short short8;
typedef __attribute__((ext_vector_type(4))) float f32x4;

static __device__ __forceinline__ unsigned short f2bf(float f) {
  union { float f; unsigned u; } v;
  v.f = f;
  unsigned r = v.u + 0x7fffu + ((v.u >> 16) & 1u);
  return (unsigned short)(r >> 16);
}
static __device__ __forceinline__ float bf2f(unsigned short h) {
  union { unsigned u; float f; } v;
  v.u = (unsigned)h << 16;
  return v.f;
}
static __device__ __forceinline__ float tanh_fast(float x) {
  float ax = fabsf(x);
  ax = fminf(ax, 20.f);
  const float e = __expf(-2.f * ax);
  const float t = (1.f - e) / (1.f + e);
  return __builtin_copysignf(t, x);
}

// async 16B global -> LDS (linear dest: wave-uniform base + lane*16)
static __device__ __forceinline__ void gload_lds16(const unsigned short* g,
                                                   unsigned short* l) {
  __builtin_amdgcn_global_load_lds(
      (const __attribute__((address_space(1))) unsigned int*)(const void*)g,
      (__attribute__((address_space(3))) unsigned int*)(void*)l, 16, 0, 0);
}

// ---------------- conv0: 3->32, reflect pad 1, 256x256 ----------------
__global__ __launch_bounds__(256) void conv0_kernel(
    const float* __restrict__ in, const float* __restrict__ w,
    const float* __restrict__ bias, float* __restrict__ out) {
  __shared__ float sw[32 * 27 + 32];
  for (int i = threadIdx.x; i < 32 * 27; i += 256) sw[i] = w[i];
  if (threadIdx.x < 32) sw[32 * 27 + threadIdx.x] = bias[threadIdx.x];
  __syncthreads();
  const int b = blockIdx.y;
  const int p = blockIdx.x * 256 + threadIdx.x;
  const int y = p >> 8, x = p & 255;
  const float* inb = in + (size_t)b * 3 * 65536;
  float v[27];
#pragma unroll
  for (int c = 0; c < 3; ++c) {
#pragma unroll
    for (int ky = 0; ky < 3; ++ky) {
      int iy = y + ky - 1;
      iy = iy < 0 ? -iy : (iy > 255 ? 510 - iy : iy);
#pragma unroll
      for (int kx = 0; kx < 3; ++kx) {
        int ix = x + kx - 1;
        ix = ix < 0 ? -ix : (ix > 255 ? 510 - ix : ix);
        v[c * 9 + ky * 3 + kx] = inb[c * 65536 + iy * 256 + ix];
      }
    }
  }
  float* ob = out + (size_t)b * 32 * 65536 + p;
#pragma unroll
  for (int co = 0; co < 32; ++co) {
    float a = sw[32 * 27 + co];
#pragma unroll
    for (int k = 0; k < 27; ++k) a = fmaf(v[k], sw[co * 27 + k], a);
    ob[(size_t)co * 65536] = a;
  }
}

// ---------------- fused instance-norm + leaky relu (in place, fp32) ----------
__global__ __launch_bounds__(256) void inorm_lrelu_kernel(float* __restrict__ x,
                                                          int HW) {
  const size_t base = (size_t)blockIdx.x * HW;
  float4* p = (float4*)(x + base);
  const int n4 = HW >> 2;
  float s = 0.f, q = 0.f;
  for (int i = threadIdx.x; i < n4; i += 256) {
    float4 v = p[i];
    s += (v.x + v.y) + (v.z + v.w);
    q += (v.x * v.x + v.y * v.y) + (v.z * v.z + v.w * v.w);
  }
  __shared__ float rs[256], rq[256];
  rs[threadIdx.x] = s;
  rq[threadIdx.x] = q;
  __syncthreads();
  for (int st = 128; st > 0; st >>= 1) {
    if (threadIdx.x < st) {
      rs[threadIdx.x] += rs[threadIdx.x + st];
      rq[threadIdx.x] += rq[threadIdx.x + st];
    }
    __syncthreads();
  }
  const float m = rs[0] / (float)HW;
  float var = rq[0] / (float)HW - m * m;
  var = var < 0.f ? 0.f : var;
  const float r = rsqrtf(var + 1e-5f);
  for (int i = threadIdx.x; i < n4; i += 256) {
    float4 v = p[i];
    v.x = (v.x - m) * r; v.x = v.x >= 0.f ? v.x : 0.2f * v.x;
    v.y = (v.y - m) * r; v.y = v.y >= 0.f ? v.y : 0.2f * v.y;
    v.z = (v.z - m) * r; v.z = v.z >= 0.f ? v.z : 0.2f * v.z;
    v.w = (v.w - m) * r; v.w = v.w >= 0.f ? v.w : 0.2f * v.w;
    p[i] = v;
  }
}

// ---------------- 3x3 stride-2 zero-pad-1 conv, 32 co per block ----------------
template <int CIN, int COUT, int HIN>
__global__ __launch_bounds__(256) void conv_s2_kernel(
    const float* __restrict__ in, const float* __restrict__ w,
    const float* __restrict__ bias, float* __restrict__ out) {
  constexpr int HOUT = HIN / 2;
  const int b = blockIdx.z;
  const int co0 = blockIdx.y * 32;
  const int p = blockIdx.x * 256 + threadIdx.x;
  const int oy = p / HOUT, ox = p % HOUT;
  float acc[32];
#pragma unroll
  for (int i = 0; i < 32; ++i) acc[i] = bias[co0 + i];
  const float* inb = in + (size_t)b * CIN * HIN * HIN;
  const int iy0 = 2 * oy - 1, ix0 = 2 * ox - 1;
  for (int ci = 0; ci < CIN; ++ci) {
    float v[9];
    const float* ip = inb + (size_t)ci * HIN * HIN;
#pragma unroll
    for (int ky = 0; ky < 3; ++ky) {
      const int iy = iy0 + ky;
      const bool yok = (unsigned)iy < (unsigned)HIN;
#pragma unroll
      for (int kx = 0; kx < 3; ++kx) {
        const int ix = ix0 + kx;
        const bool ok = yok && ((unsigned)ix < (unsigned)HIN);
        v[ky * 3 + kx] = ok ? ip[iy * HIN + ix] : 0.f;
      }
    }
    const float* wp = w + ((size_t)co0 * CIN + ci) * 9;
#pragma unroll
    for (int co = 0; co < 32; ++co) {
#pragma unroll
      for (int k = 0; k < 9; ++k)
        acc[co] = fmaf(v[k], wp[(size_t)co * CIN * 9 + k], acc[co]);
    }
  }
  float* ob = out + ((size_t)b * COUT + co0) * HOUT * HOUT + p;
#pragma unroll
  for (int co = 0; co < 32; ++co) ob[(size_t)co * HOUT * HOUT] = acc[co];
}

// -------- transpose x2: fp32 [b][128][4096] -> X2p bf16 [b][65][65][128] ----
__global__ __launch_bounds__(256) void transpose_x2_kernel(
    const float* __restrict__ x2, unsigned short* __restrict__ X2p) {
  const int b = blockIdx.y;
  const int p0 = (blockIdx.x & 63) * 64;
  const int ci0 = (blockIdx.x >> 6) * 64;
  __shared__ unsigned short T[64][66];
  const float* src = x2 + (size_t)b * 128 * 4096;
  const int t = threadIdx.x;
#pragma unroll
  for (int r = 0; r < 16; ++r) {
    const int ci_l = r * 4 + (t >> 6);
    const int p_l = t & 63;
    T[ci_l][p_l] = f2bf(src[(size_t)(ci0 + ci_l) * 4096 + p0 + p_l]);
  }
  __syncthreads();
  unsigned short* dst = X2p + (size_t)b * 65 * 65 * 128;
#pragma unroll
  for (int r = 0; r < 2; ++r) {
    const int p_l = r * 32 + (t >> 3);
    const int c0 = (t & 7) * 8;
    union { short8 v; unsigned short u[8]; } pk;
#pragma unroll
    for (int j = 0; j < 8; ++j) pk.u[j] = T[c0 + j][p_l];
    const int p = p0 + p_l;
    const int yy = p >> 6, xx = p & 63;
    *(short8*)(dst + ((size_t)yy * 65 + xx) * 128 + ci0 + c0) = pk.v;
  }
}

// ---------------- zero pad row 64 / col 64 of X2p ----------------
__global__ __launch_bounds__(256) void zpad_x2_kernel(unsigned short* __restrict__ X2p) {
  const int b = blockIdx.x;
  unsigned short* Xb = X2p + (size_t)b * 65 * 65 * 128;
  for (int i = threadIdx.x; i < 129 * 128; i += 256) {
    const int j = i >> 7, ci = i & 127;
    size_t off;
    if (j < 65) off = ((size_t)64 * 65 + j) * 128 + ci;
    else off = ((size_t)(j - 65) * 65 + 64) * 128 + ci;
    Xb[off] = 0;
  }
}

// -------- weight repack (coalesced tiles): wt fp32 [256][128][3][3] ->
// -------- Wtb2 bf16 [9][cot16][c4(4)][lane64][8] ----------------------------
__global__ __launch_bounds__(256) void wtprep_kernel(const float* __restrict__ wt,
                                                     unsigned short* __restrict__ Wtb2) {
  const int i = blockIdx.x * 256 + threadIdx.x;
  if (i >= 9 * 256 * 128) return;
  const int e = i & 7, lane = (i >> 3) & 63, c4 = (i >> 9) & 3;
  const int cot = (i >> 11) & 15, tap = i >> 15;
  const int co = cot * 16 + (lane & 15);
  const int ci = c4 * 32 + (lane >> 4) * 8 + e;
  Wtb2[i] = f2bf(wt[((size_t)co * 128 + ci) * 9 + tap]);
}

// ---------------- convT as bf16 MFMA per-parity-class GEMM ----------------
__global__ __launch_bounds__(256, 3) void convt_mfma_kernel(
    const unsigned short* __restrict__ X2p, const unsigned short* __restrict__ Wtb2,
    const float* __restrict__ bt, unsigned short* __restrict__ Y) {
  const int raw = blockIdx.x;
  const int swz = (raw & 7) * 256 + (raw >> 3);
  const int b = swz >> 8;
  const int rem = swz & 255;
  const int cls = rem >> 6;
  const int sy = rem & 63;
  const int py = cls & 1, px = cls >> 1;

  const int kyA = py ? 0 : 1, kxA = px ? 0 : 1;
  int tk[4], tdy[4], tdx[4];
  int ntaps = 0;
  tk[ntaps] = kyA * 3 + kxA; tdy[ntaps] = 0; tdx[ntaps] = 0; ++ntaps;
  if (px) { tk[ntaps] = kyA * 3 + 2; tdy[ntaps] = 0; tdx[ntaps] = 1; ++ntaps; }
  if (py) { tk[ntaps] = 6 + kxA; tdy[ntaps] = 1; tdx[ntaps] = 0; ++ntaps; }
  if (py && px) { tk[ntaps] = 8; tdy[ntaps] = 1; tdx[ntaps] = 1; ++ntaps; }

  constexpr int CS = 36;
  constexpr int BUFN = 2 * 65 * CS;
  __shared__ unsigned short As2[2 * BUFN];

  const int t = threadIdx.x;
  const int lane = t & 63;
  const int wn = t >> 6;
  const int lg = lane >> 4, lr = lane & 15;
  const int co_w = wn * 64;

  const unsigned short* Xb = X2p + (size_t)b * 65 * 65 * 128;

  int dof0, dof1, dof2;
  const unsigned short *sp0, *sp1, *sp2;
  bool sv2;
  {
    const int i0 = t, i1 = t + 256, i2 = t + 512;
    const int r0 = i0 / 260, c0_ = (i0 % 260) >> 2, h0 = i0 & 3;
    const int r1 = i1 / 260, c1_ = (i1 % 260) >> 2, h1 = i1 & 3;
    sv2 = i2 < 520;
    const int i2c = sv2 ? i2 : 512;
    const int r2 = i2c / 260, c2_ = (i2c % 260) >> 2, h2 = i2c & 3;
    dof0 = (r0 * 65 + c0_) * CS + h0 * 8;
    dof1 = (r1 * 65 + c1_) * CS + h1 * 8;
    dof2 = (r2 * 65 + c2_) * CS + h2 * 8;
    sp0 = Xb + ((size_t)(sy + r0) * 65 + c0_) * 128 + h0 * 8;
    sp1 = Xb + ((size_t)(sy + r1) * 65 + c1_) * 128 + h1 * 8;
    sp2 = Xb + ((size_t)(sy + r2) * 65 + c2_) * 128 + h2 * 8;
  }

  f32x4 acc[4][4];
#pragma unroll
  for (int mt = 0; mt < 4; ++mt)
#pragma unroll
    for (int nt = 0; nt < 4; ++nt) {
      f32x4 z = {0.f, 0.f, 0.f, 0.f};
      acc[mt][nt] = z;
    }

  {
    const short8 a = *(const short8*)sp0;
    const short8 bq = *(const short8*)sp1;
    short8 cq;
    if (sv2) cq = *(const short8*)sp2;
    *(short8*)(As2 + dof0) = a;
    *(short8*)(As2 + dof1) = bq;
    if (sv2) *(short8*)(As2 + dof2) = cq;
  }
  __syncthreads();

  const unsigned short* wlane = Wtb2 + (size_t)lane * 8;

  for (int c8 = 0; c8 < 4; ++c8) {
    short8 n0, n1, n2;
    if (c8 < 3) {
      const int cn = (c8 + 1) * 32;
      n0 = *(const short8*)(sp0 + cn);
      n1 = *(const short8*)(sp1 + cn);
      if (sv2) n2 = *(const short8*)(sp2 + cn);
    }
    const unsigned short* Ab = As2 + (c8 & 1) * BUFN;
    for (int tp = 0; tp < ntaps; ++tp) {
      const int dy = tdy[tp], dx = tdx[tp];
      short8 af[4];
#pragma unroll
      for (int mt = 0; mt < 4; ++mt)
        af[mt] = *(const short8*)(Ab + (dy * 65 + mt * 16 + lr + dx) * CS + lg * 8);
      const unsigned short* wt_ =
          wlane + (size_t)(((tk[tp] * 16 + wn * 4) * 4) + c8) * 512;
#pragma unroll
      for (int nt = 0; nt < 4; ++nt) {
        const short8 bf = *(const short8*)(wt_ + (size_t)nt * (4 * 512));
#pragma unroll
        for (int mt = 0; mt < 4; ++mt)
          acc[mt][nt] = __builtin_amdgcn_mfma_f32_16x16x32_bf16(
              af[mt], bf, acc[mt][nt], 0, 0, 0);
      }
    }
    if (c8 < 3) {
      unsigned short* Db = As2 + ((c8 + 1) & 1) * BUFN;
      *(short8*)(Db + dof0) = n0;
      *(short8*)(Db + dof1) = n1;
      if (sv2) *(short8*)(Db + dof2) = n2;
    }
    __syncthreads();
  }

  const int oy = 2 * sy + py;
  unsigned short* Yb = Y + ((size_t)b * 16384 + (size_t)oy * 128 + px) * 256;
  float bco[4];
#pragma unroll
  for (int nt = 0; nt < 4; ++nt) bco[nt] = bt[co_w + nt * 16 + lr];
#pragma unroll
  for (int mt = 0; mt < 4; ++mt) {
#pragma unroll
    for (int r = 0; r < 4; ++r) {
      const int sx = mt * 16 + lg * 4 + r;
      unsigned short* yp = Yb + (size_t)(2 * sx) * 256 + co_w + lr;
#pragma unroll
      for (int nt = 0; nt < 4; ++nt)
        yp[nt * 16] = f2bf(acc[mt][nt][r] + bco[nt]);
    }
  }
}

// ---------------- instance-norm stats over pixel-major Y ----------------
__global__ __launch_bounds__(256) void inorm_stats_kernel(
    const unsigned short* __restrict__ Y, float* __restrict__ ssum,
    float* __restrict__ ssq) {
  const int b = blockIdx.y, sl = blockIdx.x, c = threadIdx.x;
  const unsigned short* p = Y + ((size_t)b * 16384 + (size_t)sl * 1024) * 256 + c;
  float s = 0.f, q = 0.f;
  for (int i = 0; i < 1024; ++i) {
    const float v = bf2f(p[(size_t)i * 256]);
    s += v;
    q += v * v;
  }
  atomicAdd(&ssum[b * 256 + c], s);
  atomicAdd(&ssq[b * 256 + c], q);
}

// ------- apply IN + LReLU to Y, write bf16 into Xpad interior -------
__global__ __launch_bounds__(256) void inorm_apply_kernel(
    const unsigned short* __restrict__ Y, const float* __restrict__ ssum,
    const float* __restrict__ ssq, unsigned short* __restrict__ Xpad) {
  const int b = blockIdx.y, sl = blockIdx.x, c = threadIdx.x;
  const float m = ssum[b * 256 + c] * (1.f / 16384.f);
  float var = ssq[b * 256 + c] * (1.f / 16384.f) - m * m;
  var = var < 0.f ? 0.f : var;
  const float r = rsqrtf(var + 1e-5f);
  const unsigned short* p = Y + ((size_t)b * 16384 + (size_t)sl * 1024) * 256 + c;
  unsigned short* dst = Xpad + (size_t)b * 130 * 130 * 256 + c;
  for (int i = 0; i < 1024; ++i) {
    const int pix = sl * 1024 + i;
    const int yy = pix >> 7, xx = pix & 127;
    float v = bf2f(p[(size_t)i * 256]);
    v = (v - m) * r;
    v = v >= 0.f ? v : 0.2f * v;
    dst[((size_t)(yy + 1) * 130 + (xx + 1)) * 256] = f2bf(v);
  }
}

// ---------------- reflect borders of Xpad: rows then cols ----------------
__global__ __launch_bounds__(256) void pad_rows_kernel(unsigned short* __restrict__ Xp) {
  const int b = blockIdx.x >> 1, side = blockIdx.x & 1;
  unsigned short* Xb = Xp + (size_t)b * 130 * 130 * 256;
  const int dr = side ? 129 : 0, sr = side ? 127 : 2;
  for (int i = threadIdx.x; i < 4096; i += 256) {
    const int c = 1 + (i >> 5), o = (i & 31) * 8;
    *(short8*)(Xb + ((size_t)dr * 130 + c) * 256 + o) =
        *(const short8*)(Xb + ((size_t)sr * 130 + c) * 256 + o);
  }
}
__global__ __launch_bounds__(256) void pad_cols_kernel(unsigned short* __restrict__ Xp) {
  const int b = blockIdx.x >> 1, side = blockIdx.x & 1;
  unsigned short* Xb = Xp + (size_t)b * 130 * 130 * 256;
  const int dc = side ? 129 : 0, sc = side ? 127 : 2;
  for (int i = threadIdx.x; i < 130 * 32; i += 256) {
    const int r = i >> 5, o = (i & 31) * 8;
    *(short8*)(Xb + ((size_t)r * 130 + dc) * 256 + o) =
        *(const short8*)(Xb + ((size_t)r * 130 + sc) * 256 + o);
  }
}

// ------ weight repack (coalesced tiles): w3 fp32 [512][256][9] ->
// ------ Wb2 bf16 [9][cot32][c8(8)][lane64][8]; co=cot*16+lr, ci=c8*32+lg*8+e
__global__ __launch_bounds__(256) void wprep_kernel(const float* __restrict__ w3,
                                                    unsigned short* __restrict__ Wb2) {
  const int i = blockIdx.x * 256 + threadIdx.x;
  if (i >= 9 * 512 * 256) return;
  const int e = i & 7, lane = (i >> 3) & 63, c8 = (i >> 9) & 7;
  const int cot = (i >> 12) & 31, tap = i >> 17;
  const int co = cot * 16 + (lane & 15);
  const int ci = c8 * 32 + (lane >> 4) * 8 + e;
  Wb2[i] = f2bf(w3[((size_t)co * 256 + ci) * 9 + tap]);
}

// ---------------- label extraction + counts from one-hot segmap ----------------
__global__ __launch_bounds__(256) void label_kernel(
    const float* __restrict__ segmap, int* __restrict__ labels,
    float* __restrict__ cnt) {
  const int b = blockIdx.y;
  const int p = blockIdx.x * 256 + threadIdx.x;
  const int i = p >> 7, j = p & 127;
  const float* sp = segmap + (size_t)b * 19 * 65536 + (2 * i) * 256 + 2 * j;
  int lab = 0;
#pragma unroll
  for (int s = 0; s < 19; ++s)
    if (sp[(size_t)s * 65536] != 0.f) lab = s;
  labels[b * 16384 + p] = lab;
  atomicAdd(&cnt[b * 19 + lab], 1.0f);
}

// ---------------- conv3: bf16 MFMA implicit GEMM + tanh + region pool --------
// Block = 512 threads (8 waves) = one image row (128 px) x ALL 512 co.
// Wave grid 2Mx4N, wave tile 64px x 128co, acc 4x8 f32x4 = 128 regs.
// R9: A-halo staged via async global_load_lds into a LINEAR LDS layout;
// bank conflicts avoided by XOR-swizzle pair: slot (E, hs) holds global
// ci-quarter hs ^ ((E>>1)&3); reads use the same involution. B-fragments
// bf[8] all live across each tap's 32-MFMA cluster (registers now fit).
__global__ __launch_bounds__(512, 2) void conv3_mfma_pool_kernel(
    const unsigned short* __restrict__ Xpad, const unsigned short* __restrict__ Wb2,
    const float* __restrict__ bias, const int* __restrict__ labels,
    float* __restrict__ sums) {
  // XCD swizzle: 1024 = 8 XCDs x 128 -> one batch per XCD
  const int raw = blockIdx.x;
  const int swz = (raw & 7) * 128 + (raw >> 3);
  const int b = swz >> 7;
  const int y = swz & 127;

  constexpr int SLOTS = 1600;  // 1560 used (3*130*4) + tail pad
  __shared__ unsigned short Asw[2 * SLOTS * 8];  // 51.2 KB
  float* lsum = (float*)Asw;                     // epilogue reuse (38.9 KB)

  const int t = threadIdx.x;
  const int lane = t & 63;
  const int wave = t >> 6;     // 0..7
  const int wm = wave >> 2;    // 0..1: M group (64 px)
  const int wn = wave & 3;     // 0..3: N group (128 co)
  const int lg = lane >> 4, lr = lane & 15;
  const int co_w = wn * 128;

  const unsigned short* Xb = Xpad + (size_t)b * 130 * 130 * 256;

  // per-thread global sources for slots t, t+512, t+1024, (1536+lane for wave0)
  // slot s = E*4 + hs (E = r*130+c); stored quarter h = hs ^ ((E>>1)&3)
  const unsigned short *sp0, *sp1, *sp2, *sp3;
  {
    const int ss[4] = {t, t + 512, t + 1024,
                       (t + 1536 < 1560) ? (t + 1536) : 1536};
    const unsigned short* sp[4];
#pragma unroll
    for (int k = 0; k < 4; ++k) {
      const int s = ss[k];
      const int r = s / 520, rem = s % 520, c = rem >> 2, hs = rem & 3;
      const int E = r * 130 + c;
      const int h = hs ^ ((E >> 1) & 3);
      sp[k] = Xb + ((size_t)(y + r) * 130 + c) * 256 + h * 8;
    }
    sp0 = sp[0]; sp1 = sp[1]; sp2 = sp[2]; sp3 = sp[3];
  }

  f32x4 acc[4][8];
#pragma unroll
  for (int mt = 0; mt < 4; ++mt)
#pragma unroll
    for (int nt = 0; nt < 8; ++nt) {
      f32x4 z = {0.f, 0.f, 0.f, 0.f};
      acc[mt][nt] = z;
    }

  const unsigned short* wlane = Wb2 + (size_t)lane * 8;

  // async stage of one 32-ci chunk into buffer `bufSel` (ci offset `off`)
  const int wslot = wave * 64;
#define STAGE(bufSel, off)                                                   \
  {                                                                          \
    unsigned short* base_ = Asw + (bufSel) * (SLOTS * 8);                    \
    gload_lds16(sp0 + (off), base_ + (size_t)wslot * 8);                     \
    gload_lds16(sp1 + (off), base_ + (size_t)(wslot + 512) * 8);             \
    gload_lds16(sp2 + (off), base_ + (size_t)(wslot + 1024) * 8);            \
    if (wave == 0 && lane < 24)                                              \
      gload_lds16(sp3 + (off), base_ + (size_t)1536 * 8);                    \
  }

  STAGE(0, 0)
  __syncthreads();

  for (int c8 = 0; c8 < 8; ++c8) {
    if (c8 < 7) STAGE((c8 + 1) & 1, (c8 + 1) * 32)
    const unsigned short* Ab = Asw + (c8 & 1) * (SLOTS * 8);
#pragma unroll
    for (int ky = 0; ky < 3; ++ky) {
#pragma unroll
      for (int kx = 0; kx < 3; ++kx) {
        const unsigned short* wt_ =
            wlane + (size_t)(((ky * 3 + kx) * 32 + wn * 8) * 8 + c8) * 512;
        short8 bfv[8];
#pragma unroll
        for (int nt = 0; nt < 8; ++nt)
          bfv[nt] = *(const short8*)(wt_ + (size_t)nt * (8 * 512));
        short8 af[4];
#pragma unroll
        for (int mt = 0; mt < 4; ++mt) {
          const int E = ky * 130 + wm * 64 + mt * 16 + lr + kx;
          const int hh = lg ^ ((E >> 1) & 3);
          af[mt] = *(const short8*)(Ab + (size_t)E * 32 + hh * 8);
        }
#pragma unroll
        for (int nt = 0; nt < 8; ++nt) {
#pragma unroll
          for (int mt = 0; mt < 4; ++mt)
            acc[mt][nt] = __builtin_amdgcn_mfma_f32_16x16x32_bf16(
                af[mt], bfv[nt], acc[mt][nt], 0, 0, 0);
        }
      }
    }
    __syncthreads();
  }
#undef STAGE

  // epilogue: staging LDS dead -> zero lsum in same space
  for (int i = t; i < 19 * 512; i += 512) lsum[i] = 0.f;
  __syncthreads();

  const int* labp = labels + b * 16384 + y * 128;
  float bco[8];
#pragma unroll
  for (int nt = 0; nt < 8; ++nt) bco[nt] = bias[co_w + nt * 16 + lr];
#pragma unroll
  for (int mt = 0; mt < 4; ++mt) {
#pragma unroll
    for (int r = 0; r < 4; ++r) {
      const int lab = labp[wm * 64 + mt * 16 + lg * 4 + r];
#pragma unroll
      for (int nt = 0; nt < 8; ++nt) {
        const float v = tanh_fast(acc[mt][nt][r] + bco[nt]);
        atomicAdd(&lsum[lab * 512 + co_w + nt * 16 + lr], v);
      }
    }
  }
  __syncthreads();
  for (int i = t; i < 19 * 512; i += 512) {
    const float v = lsum[i];
    if (v != 0.f) {
      const int sI = i >> 9, c = i & 511;
      atomicAdd(&sums[((size_t)b * 19 + sI) * 512 + c], v);
    }
  }
}

// ---------------- finalize: out = cnt>0 ? sums/max(cnt,1) : 0 ----------------
__global__ __launch_bounds__(256) void finalize_kernel(
    const float* __restrict__ sums, const float* __restrict__ cnt,
    float* __restrict__ out) {
  const int i = blockIdx.x * 256 + threadIdx.x;
  if (i >= B * 19 * 512) return;
  const int bs = i >> 9;
  const float c = cnt[bs];
  out[i] = c > 0.f ? sums[i] / fmaxf(c, 1.f) : 0.f;
}

// ---------------------------------------------------------------------------
extern "C" void kernel_launch(void* const* d_in, const int* in_sizes, int n_in,
                              void* d_out, int out_size, void* d_ws,
                              size_t ws_size, hipStream_t stream) {
  const float* input = (const float*)d_in[0];
  const float* segmap = (const float*)d_in[1];
  const float* w0 = (const float*)d_in[2];
  const float* b0 = (const float*)d_in[3];
  const float* w1 = (const float*)d_in[4];
  const float* b1 = (const float*)d_in[5];
  const float* w2 = (const float*)d_in[6];
  const float* b2 = (const float*)d_in[7];
  const float* wt = (const float*)d_in[8];
  const float* bt = (const float*)d_in[9];
  const float* w3 = (const float*)d_in[10];
  const float* b3 = (const float*)d_in[11];
  float* out = (float*)d_out;

  float* ws = (float*)d_ws;
  float* x0 = ws;                                    // 16,777,216 f
  float* x1 = x0 + 16777216;                         //  8,388,608 f
  float* x2 = x1 + 8388608;                          //  4,194,304 f
  unsigned short* X2p = (unsigned short*)(x2 + 4194304);  // 4,326,400 us
  unsigned short* Y = X2p + 4326400;                 // 33,554,432 us
  float* sums = (float*)(Y + 33554432);              //     77,824 f
  float* cnt = sums + 77824;                         //        152 f
  float* ssum = cnt + 152;                           //      2,048 f
  float* ssq = ssum + 2048;                          //      2,048 f
  int* labels = (int*)(ssq + 2048);                  //    131,072 i
  unsigned short* Wb2 = (unsigned short*)(labels + 131072);  // 1,179,648 us
  unsigned short* Wtb2 = Wb2 + 1179648;              //    294,912 us
  unsigned short* Xpad = (unsigned short*)ws;        // 69.2MB over x0+x1 (dead)

  hipMemsetAsync(sums, 0, (77824 + 152 + 2048 + 2048) * sizeof(float), stream);

  wprep_kernel<<<dim3((9 * 512 * 256 + 255) / 256), 256, 0, stream>>>(w3, Wb2);
  wtprep_kernel<<<dim3((9 * 256 * 128 + 255) / 256), 256, 0, stream>>>(wt, Wtb2);
  conv0_kernel<<<dim3(256, B), 256, 0, stream>>>(input, w0, b0, x0);
  inorm_lrelu_kernel<<<dim3(B * 32), 256, 0, stream>>>(x0, 65536);
  conv_s2_kernel<32, 64, 256><<<dim3(64, 2, B), 256, 0, stream>>>(x0, w1, b1, x1);
  inorm_lrelu_kernel<<<dim3(B * 64), 256, 0, stream>>>(x1, 16384);
  conv_s2_kernel<64, 128, 128><<<dim3(16, 4, B), 256, 0, stream>>>(x1, w2, b2, x2);
  inorm_lrelu_kernel<<<dim3(B * 128), 256, 0, stream>>>(x2, 4096);
  transpose_x2_kernel<<<dim3(128, B), 256, 0, stream>>>(x2, X2p);
  zpad_x2_kernel<<<dim3(B), 256, 0, stream>>>(X2p);
  convt_mfma_kernel<<<dim3(2048), 256, 0, stream>>>(X2p, Wtb2, bt, Y);
  inorm_stats_kernel<<<dim3(16, B), 256, 0, stream>>>(Y, ssum, ssq);
  inorm_apply_kernel<<<dim3(16, B), 256, 0, stream>>>(Y, ssum, ssq, Xpad);
  pad_rows_kernel<<<dim3(2 * B), 256, 0, stream>>>(Xpad);
  pad_cols_kernel<<<dim3(2 * B), 256, 0, stream>>>(Xpad);
  label_kernel<<<dim3(64, B), 256, 0, stream>>>(segmap, labels, cnt);
  conv3_mfma_pool_kernel<<<dim3(1024), 512, 0, stream>>>(Xpad, Wb2, b3, labels, sums);
  finalize_kernel<<<dim3((B * 19 * 512 + 255) / 256), 256, 0, stream>>>(sums, cnt, out);
}

// Round 10
// 1359.721 us; speedup vs baseline: 1.4985x; 1.0230x over previous
//
#include <hip/hip_runtime.h>

// ---------------------------------------------------------------------------
// SPADE-style encoder.
// conv3: bf16 MFMA implicit-GEMM. R10: block re-tiled 8-wave -> 4-wave
//        (128px x 256co, wave tile 64x128 unchanged) so 2 blocks co-reside
//        per CU (R9 had 1 block/CU -> every barrier drain stalled the CU).
//        A-halo via async global_load_lds (XOR-swizzled src/read pair),
//        coalesced B tiles, lsum unioned with staging LDS.
// convT: bf16 MFMA per-parity-class GEMM with coalesced B tiles.
// conv0/conv1/conv2 + their instance-norms still fp32 vector.
// ---------------------------------------------------------------------------

#define B 8

typedef __attribute__((ext_vector_type(8))) short short8;
typedef __attribute__((ext_vector_type(4))) float f32x4;

static __device__ __forceinline__ unsigned short f2bf(float f) {
  union { float f; unsigned u; } v;
  v.f = f;
  unsigned r = v.u + 0x7fffu + ((v.u >> 16) & 1u);
  return (unsigned short)(r >> 16);
}
static __device__ __forceinline__ float bf2f(unsigned short h) {
  union { unsigned u; float f; } v;
  v.u = (unsigned)h << 16;
  return v.f;
}
static __device__ __forceinline__ float tanh_fast(float x) {
  float ax = fabsf(x);
  ax = fminf(ax, 20.f);
  const float e = __expf(-2.f * ax);
  const float t = (1.f - e) / (1.f + e);
  return __builtin_copysignf(t, x);
}

// async 16B global -> LDS (linear dest: wave-uniform base + lane*16)
static __device__ __forceinline__ void gload_lds16(const unsigned short* g,
                                                   unsigned short* l) {
  __builtin_amdgcn_global_load_lds(
      (const __attribute__((address_space(1))) unsigned int*)(const void*)g,
      (__attribute__((address_space(3))) unsigned int*)(void*)l, 16, 0, 0);
}

// ---------------- conv0: 3->32, reflect pad 1, 256x256 ----------------
__global__ __launch_bounds__(256) void conv0_kernel(
    const float* __restrict__ in, const float* __restrict__ w,
    const float* __restrict__ bias, float* __restrict__ out) {
  __shared__ float sw[32 * 27 + 32];
  for (int i = threadIdx.x; i < 32 * 27; i += 256) sw[i] = w[i];
  if (threadIdx.x < 32) sw[32 * 27 + threadIdx.x] = bias[threadIdx.x];
  __syncthreads();
  const int b = blockIdx.y;
  const int p = blockIdx.x * 256 + threadIdx.x;
  const int y = p >> 8, x = p & 255;
  const float* inb = in + (size_t)b * 3 * 65536;
  float v[27];
#pragma unroll
  for (int c = 0; c < 3; ++c) {
#pragma unroll
    for (int ky = 0; ky < 3; ++ky) {
      int iy = y + ky - 1;
      iy = iy < 0 ? -iy : (iy > 255 ? 510 - iy : iy);
#pragma unroll
      for (int kx = 0; kx < 3; ++kx) {
        int ix = x + kx - 1;
        ix = ix < 0 ? -ix : (ix > 255 ? 510 - ix : ix);
        v[c * 9 + ky * 3 + kx] = inb[c * 65536 + iy * 256 + ix];
      }
    }
  }
  float* ob = out + (size_t)b * 32 * 65536 + p;
#pragma unroll
  for (int co = 0; co < 32; ++co) {
    float a = sw[32 * 27 + co];
#pragma unroll
    for (int k = 0; k < 27; ++k) a = fmaf(v[k], sw[co * 27 + k], a);
    ob[(size_t)co * 65536] = a;
  }
}

// ---------------- fused instance-norm + leaky relu (in place, fp32) ----------
__global__ __launch_bounds__(256) void inorm_lrelu_kernel(float* __restrict__ x,
                                                          int HW) {
  const size_t base = (size_t)blockIdx.x * HW;
  float4* p = (float4*)(x + base);
  const int n4 = HW >> 2;
  float s = 0.f, q = 0.f;
  for (int i = threadIdx.x; i < n4; i += 256) {
    float4 v = p[i];
    s += (v.x + v.y) + (v.z + v.w);
    q += (v.x * v.x + v.y * v.y) + (v.z * v.z + v.w * v.w);
  }
  __shared__ float rs[256], rq[256];
  rs[threadIdx.x] = s;
  rq[threadIdx.x] = q;
  __syncthreads();
  for (int st = 128; st > 0; st >>= 1) {
    if (threadIdx.x < st) {
      rs[threadIdx.x] += rs[threadIdx.x + st];
      rq[threadIdx.x] += rq[threadIdx.x + st];
    }
    __syncthreads();
  }
  const float m = rs[0] / (float)HW;
  float var = rq[0] / (float)HW - m * m;
  var = var < 0.f ? 0.f : var;
  const float r = rsqrtf(var + 1e-5f);
  for (int i = threadIdx.x; i < n4; i += 256) {
    float4 v = p[i];
    v.x = (v.x - m) * r; v.x = v.x >= 0.f ? v.x : 0.2f * v.x;
    v.y = (v.y - m) * r; v.y = v.y >= 0.f ? v.y : 0.2f * v.y;
    v.z = (v.z - m) * r; v.z = v.z >= 0.f ? v.z : 0.2f * v.z;
    v.w = (v.w - m) * r; v.w = v.w >= 0.f ? v.w : 0.2f * v.w;
    p[i] = v;
  }
}

// ---------------- 3x3 stride-2 zero-pad-1 conv, 32 co per block ----------------
template <int CIN, int COUT, int HIN>
__global__ __launch_bounds__(256) void conv_s2_kernel(
    const float* __restrict__ in, const float* __restrict__ w,
    const float* __restrict__ bias, float* __restrict__ out) {
  constexpr int HOUT = HIN / 2;
  const int b = blockIdx.z;
  const int co0 = blockIdx.y * 32;
  const int p = blockIdx.x * 256 + threadIdx.x;
  const int oy = p / HOUT, ox = p % HOUT;
  float acc[32];
#pragma unroll
  for (int i = 0; i < 32; ++i) acc[i] = bias[co0 + i];
  const float* inb = in + (size_t)b * CIN * HIN * HIN;
  const int iy0 = 2 * oy - 1, ix0 = 2 * ox - 1;
  for (int ci = 0; ci < CIN; ++ci) {
    float v[9];
    const float* ip = inb + (size_t)ci * HIN * HIN;
#pragma unroll
    for (int ky = 0; ky < 3; ++ky) {
      const int iy = iy0 + ky;
      const bool yok = (unsigned)iy < (unsigned)HIN;
#pragma unroll
      for (int kx = 0; kx < 3; ++kx) {
        const int ix = ix0 + kx;
        const bool ok = yok && ((unsigned)ix < (unsigned)HIN);
        v[ky * 3 + kx] = ok ? ip[iy * HIN + ix] : 0.f;
      }
    }
    const float* wp = w + ((size_t)co0 * CIN + ci) * 9;
#pragma unroll
    for (int co = 0; co < 32; ++co) {
#pragma unroll
      for (int k = 0; k < 9; ++k)
        acc[co] = fmaf(v[k], wp[(size_t)co * CIN * 9 + k], acc[co]);
    }
  }
  float* ob = out + ((size_t)b * COUT + co0) * HOUT * HOUT + p;
#pragma unroll
  for (int co = 0; co < 32; ++co) ob[(size_t)co * HOUT * HOUT] = acc[co];
}

// -------- transpose x2: fp32 [b][128][4096] -> X2p bf16 [b][65][65][128] ----
__global__ __launch_bounds__(256) void transpose_x2_kernel(
    const float* __restrict__ x2, unsigned short* __restrict__ X2p) {
  const int b = blockIdx.y;
  const int p0 = (blockIdx.x & 63) * 64;
  const int ci0 = (blockIdx.x >> 6) * 64;
  __shared__ unsigned short T[64][66];
  const float* src = x2 + (size_t)b * 128 * 4096;
  const int t = threadIdx.x;
#pragma unroll
  for (int r = 0; r < 16; ++r) {
    const int ci_l = r * 4 + (t >> 6);
    const int p_l = t & 63;
    T[ci_l][p_l] = f2bf(src[(size_t)(ci0 + ci_l) * 4096 + p0 + p_l]);
  }
  __syncthreads();
  unsigned short* dst = X2p + (size_t)b * 65 * 65 * 128;
#pragma unroll
  for (int r = 0; r < 2; ++r) {
    const int p_l = r * 32 + (t >> 3);
    const int c0 = (t & 7) * 8;
    union { short8 v; unsigned short u[8]; } pk;
#pragma unroll
    for (int j = 0; j < 8; ++j) pk.u[j] = T[c0 + j][p_l];
    const int p = p0 + p_l;
    const int yy = p >> 6, xx = p & 63;
    *(short8*)(dst + ((size_t)yy * 65 + xx) * 128 + ci0 + c0) = pk.v;
  }
}

// ---------------- zero pad row 64 / col 64 of X2p ----------------
__global__ __launch_bounds__(256) void zpad_x2_kernel(unsigned short* __restrict__ X2p) {
  const int b = blockIdx.x;
  unsigned short* Xb = X2p + (size_t)b * 65 * 65 * 128;
  for (int i = threadIdx.x; i < 129 * 128; i += 256) {
    const int j = i >> 7, ci = i & 127;
    size_t off;
    if (j < 65) off = ((size_t)64 * 65 + j) * 128 + ci;
    else off = ((size_t)(j - 65) * 65 + 64) * 128 + ci;
    Xb[off] = 0;
  }
}

// -------- weight repack (coalesced tiles): wt fp32 [256][128][3][3] ->
// -------- Wtb2 bf16 [9][cot16][c4(4)][lane64][8] ----------------------------
__global__ __launch_bounds__(256) void wtprep_kernel(const float* __restrict__ wt,
                                                     unsigned short* __restrict__ Wtb2) {
  const int i = blockIdx.x * 256 + threadIdx.x;
  if (i >= 9 * 256 * 128) return;
  const int e = i & 7, lane = (i >> 3) & 63, c4 = (i >> 9) & 3;
  const int cot = (i >> 11) & 15, tap = i >> 15;
  const int co = cot * 16 + (lane & 15);
  const int ci = c4 * 32 + (lane >> 4) * 8 + e;
  Wtb2[i] = f2bf(wt[((size_t)co * 128 + ci) * 9 + tap]);
}

// ---------------- convT as bf16 MFMA per-parity-class GEMM ----------------
__global__ __launch_bounds__(256, 3) void convt_mfma_kernel(
    const unsigned short* __restrict__ X2p, const unsigned short* __restrict__ Wtb2,
    const float* __restrict__ bt, unsigned short* __restrict__ Y) {
  const int raw = blockIdx.x;
  const int swz = (raw & 7) * 256 + (raw >> 3);
  const int b = swz >> 8;
  const int rem = swz & 255;
  const int cls = rem >> 6;
  const int sy = rem & 63;
  const int py = cls & 1, px = cls >> 1;

  const int kyA = py ? 0 : 1, kxA = px ? 0 : 1;
  int tk[4], tdy[4], tdx[4];
  int ntaps = 0;
  tk[ntaps] = kyA * 3 + kxA; tdy[ntaps] = 0; tdx[ntaps] = 0; ++ntaps;
  if (px) { tk[ntaps] = kyA * 3 + 2; tdy[ntaps] = 0; tdx[ntaps] = 1; ++ntaps; }
  if (py) { tk[ntaps] = 6 + kxA; tdy[ntaps] = 1; tdx[ntaps] = 0; ++ntaps; }
  if (py && px) { tk[ntaps] = 8; tdy[ntaps] = 1; tdx[ntaps] = 1; ++ntaps; }

  constexpr int CS = 36;
  constexpr int BUFN = 2 * 65 * CS;
  __shared__ unsigned short As2[2 * BUFN];

  const int t = threadIdx.x;
  const int lane = t & 63;
  const int wn = t >> 6;
  const int lg = lane >> 4, lr = lane & 15;
  const int co_w = wn * 64;

  const unsigned short* Xb = X2p + (size_t)b * 65 * 65 * 128;

  int dof0, dof1, dof2;
  const unsigned short *sp0, *sp1, *sp2;
  bool sv2;
  {
    const int i0 = t, i1 = t + 256, i2 = t + 512;
    const int r0 = i0 / 260, c0_ = (i0 % 260) >> 2, h0 = i0 & 3;
    const int r1 = i1 / 260, c1_ = (i1 % 260) >> 2, h1 = i1 & 3;
    sv2 = i2 < 520;
    const int i2c = sv2 ? i2 : 512;
    const int r2 = i2c / 260, c2_ = (i2c % 260) >> 2, h2 = i2c & 3;
    dof0 = (r0 * 65 + c0_) * CS + h0 * 8;
    dof1 = (r1 * 65 + c1_) * CS + h1 * 8;
    dof2 = (r2 * 65 + c2_) * CS + h2 * 8;
    sp0 = Xb + ((size_t)(sy + r0) * 65 + c0_) * 128 + h0 * 8;
    sp1 = Xb + ((size_t)(sy + r1) * 65 + c1_) * 128 + h1 * 8;
    sp2 = Xb + ((size_t)(sy + r2) * 65 + c2_) * 128 + h2 * 8;
  }

  f32x4 acc[4][4];
#pragma unroll
  for (int mt = 0; mt < 4; ++mt)
#pragma unroll
    for (int nt = 0; nt < 4; ++nt) {
      f32x4 z = {0.f, 0.f, 0.f, 0.f};
      acc[mt][nt] = z;
    }

  {
    const short8 a = *(const short8*)sp0;
    const short8 bq = *(const short8*)sp1;
    short8 cq;
    if (sv2) cq = *(const short8*)sp2;
    *(short8*)(As2 + dof0) = a;
    *(short8*)(As2 + dof1) = bq;
    if (sv2) *(short8*)(As2 + dof2) = cq;
  }
  __syncthreads();

  const unsigned short* wlane = Wtb2 + (size_t)lane * 8;

  for (int c8 = 0; c8 < 4; ++c8) {
    short8 n0, n1, n2;
    if (c8 < 3) {
      const int cn = (c8 + 1) * 32;
      n0 = *(const short8*)(sp0 + cn);
      n1 = *(const short8*)(sp1 + cn);
      if (sv2) n2 = *(const short8*)(sp2 + cn);
    }
    const unsigned short* Ab = As2 + (c8 & 1) * BUFN;
    for (int tp = 0; tp < ntaps; ++tp) {
      const int dy = tdy[tp], dx = tdx[tp];
      short8 af[4];
#pragma unroll
      for (int mt = 0; mt < 4; ++mt)
        af[mt] = *(const short8*)(Ab + (dy * 65 + mt * 16 + lr + dx) * CS + lg * 8);
      const unsigned short* wt_ =
          wlane + (size_t)(((tk[tp] * 16 + wn * 4) * 4) + c8) * 512;
#pragma unroll
      for (int nt = 0; nt < 4; ++nt) {
        const short8 bf = *(const short8*)(wt_ + (size_t)nt * (4 * 512));
#pragma unroll
        for (int mt = 0; mt < 4; ++mt)
          acc[mt][nt] = __builtin_amdgcn_mfma_f32_16x16x32_bf16(
              af[mt], bf, acc[mt][nt], 0, 0, 0);
      }
    }
    if (c8 < 3) {
      unsigned short* Db = As2 + ((c8 + 1) & 1) * BUFN;
      *(short8*)(Db + dof0) = n0;
      *(short8*)(Db + dof1) = n1;
      if (sv2) *(short8*)(Db + dof2) = n2;
    }
    __syncthreads();
  }

  const int oy = 2 * sy + py;
  unsigned short* Yb = Y + ((size_t)b * 16384 + (size_t)oy * 128 + px) * 256;
  float bco[4];
#pragma unroll
  for (int nt = 0; nt < 4; ++nt) bco[nt] = bt[co_w + nt * 16 + lr];
#pragma unroll
  for (int mt = 0; mt < 4; ++mt) {
#pragma unroll
    for (int r = 0; r < 4; ++r) {
      const int sx = mt * 16 + lg * 4 + r;
      unsigned short* yp = Yb + (size_t)(2 * sx) * 256 + co_w + lr;
#pragma unroll
      for (int nt = 0; nt < 4; ++nt)
        yp[nt * 16] = f2bf(acc[mt][nt][r] + bco[nt]);
    }
  }
}

// ---------------- instance-norm stats over pixel-major Y ----------------
__global__ __launch_bounds__(256) void inorm_stats_kernel(
    const unsigned short* __restrict__ Y, float* __restrict__ ssum,
    float* __restrict__ ssq) {
  const int b = blockIdx.y, sl = blockIdx.x, c = threadIdx.x;
  const unsigned short* p = Y + ((size_t)b * 16384 + (size_t)sl * 1024) * 256 + c;
  float s = 0.f, q = 0.f;
  for (int i = 0; i < 1024; ++i) {
    const float v = bf2f(p[(size_t)i * 256]);
    s += v;
    q += v * v;
  }
  atomicAdd(&ssum[b * 256 + c], s);
  atomicAdd(&ssq[b * 256 + c], q);
}

// ------- apply IN + LReLU to Y, write bf16 into Xpad interior -------
__global__ __launch_bounds__(256) void inorm_apply_kernel(
    const unsigned short* __restrict__ Y, const float* __restrict__ ssum,
    const float* __restrict__ ssq, unsigned short* __restrict__ Xpad) {
  const int b = blockIdx.y, sl = blockIdx.x, c = threadIdx.x;
  const float m = ssum[b * 256 + c] * (1.f / 16384.f);
  float var = ssq[b * 256 + c] * (1.f / 16384.f) - m * m;
  var = var < 0.f ? 0.f : var;
  const float r = rsqrtf(var + 1e-5f);
  const unsigned short* p = Y + ((size_t)b * 16384 + (size_t)sl * 1024) * 256 + c;
  unsigned short* dst = Xpad + (size_t)b * 130 * 130 * 256 + c;
  for (int i = 0; i < 1024; ++i) {
    const int pix = sl * 1024 + i;
    const int yy = pix >> 7, xx = pix & 127;
    float v = bf2f(p[(size_t)i * 256]);
    v = (v - m) * r;
    v = v >= 0.f ? v : 0.2f * v;
    dst[((size_t)(yy + 1) * 130 + (xx + 1)) * 256] = f2bf(v);
  }
}

// ---------------- reflect borders of Xpad: rows then cols ----------------
__global__ __launch_bounds__(256) void pad_rows_kernel(unsigned short* __restrict__ Xp) {
  const int b = blockIdx.x >> 1, side = blockIdx.x & 1;
  unsigned short* Xb = Xp + (size_t)b * 130 * 130 * 256;
  const int dr = side ? 129 : 0, sr = side ? 127 : 2;
  for (int i = threadIdx.x; i < 4096; i += 256) {
    const int c = 1 + (i >> 5), o = (i & 31) * 8;
    *(short8*)(Xb + ((size_t)dr * 130 + c) * 256 + o) =
        *(const short8*)(Xb + ((size_t)sr * 130 + c) * 256 + o);
  }
}
__global__ __launch_bounds__(256) void pad_cols_kernel(unsigned short* __restrict__ Xp) {
  const int b = blockIdx.x >> 1, side = blockIdx.x & 1;
  unsigned short* Xb = Xp + (size_t)b * 130 * 130 * 256;
  const int dc = side ? 129 : 0, sc = side ? 127 : 2;
  for (int i = threadIdx.x; i < 130 * 32; i += 256) {
    const int r = i >> 5, o = (i & 31) * 8;
    *(short8*)(Xb + ((size_t)r * 130 + dc) * 256 + o) =
        *(const short8*)(Xb + ((size_t)r * 130 + sc) * 256 + o);
  }
}

// ------ weight repack (coalesced tiles): w3 fp32 [512][256][9] ->
// ------ Wb2 bf16 [9][cot32][c8(8)][lane64][8]; co=cot*16+lr, ci=c8*32+lg*8+e
__global__ __launch_bounds__(256) void wprep_kernel(const float* __restrict__ w3,
                                                    unsigned short* __restrict__ Wb2) {
  const int i = blockIdx.x * 256 + threadIdx.x;
  if (i >= 9 * 512 * 256) return;
  const int e = i & 7, lane = (i >> 3) & 63, c8 = (i >> 9) & 7;
  const int cot = (i >> 12) & 31, tap = i >> 17;
  const int co = cot * 16 + (lane & 15);
  const int ci = c8 * 32 + (lane >> 4) * 8 + e;
  Wb2[i] = f2bf(w3[((size_t)co * 256 + ci) * 9 + tap]);
}

// ---------------- label extraction + counts from one-hot segmap ----------------
__global__ __launch_bounds__(256) void label_kernel(
    const float* __restrict__ segmap, int* __restrict__ labels,
    float* __restrict__ cnt) {
  const int b = blockIdx.y;
  const int p = blockIdx.x * 256 + threadIdx.x;
  const int i = p >> 7, j = p & 127;
  const float* sp = segmap + (size_t)b * 19 * 65536 + (2 * i) * 256 + 2 * j;
  int lab = 0;
#pragma unroll
  for (int s = 0; s < 19; ++s)
    if (sp[(size_t)s * 65536] != 0.f) lab = s;
  labels[b * 16384 + p] = lab;
  atomicAdd(&cnt[b * 19 + lab], 1.0f);
}

// ---------------- conv3: bf16 MFMA implicit GEMM + tanh + region pool --------
// R10: Block = 256 threads (4 waves) = one image row (128 px) x 256 co.
// Wave grid 2Mx2N, wave tile 64px x 128co, acc 4x8 f32x4 = 128 regs/wave.
// 228 regs/wave -> 2 waves/SIMD -> TWO blocks co-resident per CU: one
// block's barrier drain overlaps the other's MFMA stream (R9 had 1 block).
// A-halo async global_load_lds, XOR-swizzle pair: slot (E,hs) holds global
// ci-quarter hs ^ ((E>>1)&3); reads apply the same involution.
__global__ __launch_bounds__(256, 2) void conv3_mfma_pool_kernel(
    const unsigned short* __restrict__ Xpad, const unsigned short* __restrict__ Wb2,
    const float* __restrict__ bias, const int* __restrict__ labels,
    float* __restrict__ sums) {
  // XCD swizzle: 2048 = 8 XCDs x 256 -> one batch per XCD
  const int raw = blockIdx.x;
  const int swz = (raw & 7) * 256 + (raw >> 3);
  const int b = swz >> 8;
  const int rem = swz & 255;
  const int y = rem >> 1;
  const int coh = rem & 1;

  constexpr int SLOTS = 1600;  // 1560 used (3*130*4) + tail pad
  __shared__ unsigned short Asw[2 * SLOTS * 8];  // 51.2 KB
  float* lsum = (float*)Asw;                     // epilogue reuse (19.4 KB)

  const int t = threadIdx.x;
  const int lane = t & 63;
  const int wave = t >> 6;     // 0..3
  const int wm = wave >> 1;    // 0..1: M group (64 px)
  const int wn = wave & 1;     // 0..1: N group (128 co)
  const int lg = lane >> 4, lr = lane & 15;
  const int co_w = coh * 256 + wn * 128;

  const unsigned short* Xb = Xpad + (size_t)b * 130 * 130 * 256;

  // per-thread global sources: slots t+k*256 (k=0..5) + tail (wave0, lane<24)
  // slot s = E*4 + hs (E = r*130+c); stored quarter h = hs ^ ((E>>1)&3)
  const unsigned short* sp[7];
  {
#pragma unroll
    for (int k = 0; k < 7; ++k) {
      int s;
      if (k < 6) s = t + k * 256;
      else s = (t < 24) ? (1536 + t) : 1536;
      const int r = s / 520, rm = s % 520, c = rm >> 2, hs = rm & 3;
      const int E = r * 130 + c;
      const int h = hs ^ ((E >> 1) & 3);
      sp[k] = Xb + ((size_t)(y + r) * 130 + c) * 256 + h * 8;
    }
  }

  f32x4 acc[4][8];
#pragma unroll
  for (int mt = 0; mt < 4; ++mt)
#pragma unroll
    for (int nt = 0; nt < 8; ++nt) {
      f32x4 z = {0.f, 0.f, 0.f, 0.f};
      acc[mt][nt] = z;
    }

  const unsigned short* wlane = Wb2 + (size_t)lane * 8;

  // async stage of one 32-ci chunk into buffer `bufSel` (ci offset `off`)
  const int wslot = wave * 64;
#define STAGE(bufSel, off)                                                   \
  {                                                                          \
    unsigned short* base_ = Asw + (bufSel) * (SLOTS * 8);                    \
    gload_lds16(sp[0] + (off), base_ + (size_t)wslot * 8);                   \
    gload_lds16(sp[1] + (off), base_ + (size_t)(wslot + 256) * 8);           \
    gload_lds16(sp[2] + (off), base_ + (size_t)(wslot + 512) * 8);           \
    gload_lds16(sp[3] + (off), base_ + (size_t)(wslot + 768) * 8);           \
    gload_lds16(sp[4] + (off), base_ + (size_t)(wslot + 1024) * 8);          \
    gload_lds16(sp[5] + (off), base_ + (size_t)(wslot + 1280) * 8);          \
    if (wave == 0 && lane < 24)                                              \
      gload_lds16(sp[6] + (off), base_ + (size_t)1536 * 8);                  \
  }

  STAGE(0, 0)
  __syncthreads();

  for (int c8 = 0; c8 < 8; ++c8) {
    if (c8 < 7) STAGE((c8 + 1) & 1, (c8 + 1) * 32)
    const unsigned short* Ab = Asw + (c8 & 1) * (SLOTS * 8);
#pragma unroll
    for (int ky = 0; ky < 3; ++ky) {
#pragma unroll
      for (int kx = 0; kx < 3; ++kx) {
        const unsigned short* wt_ =
            wlane +
            (size_t)(((ky * 3 + kx) * 32 + coh * 16 + wn * 8) * 8 + c8) * 512;
        short8 bfv[8];
#pragma unroll
        for (int nt = 0; nt < 8; ++nt)
          bfv[nt] = *(const short8*)(wt_ + (size_t)nt * (8 * 512));
        short8 af[4];
#pragma unroll
        for (int mt = 0; mt < 4; ++mt) {
          const int E = ky * 130 + wm * 64 + mt * 16 + lr + kx;
          const int hh = lg ^ ((E >> 1) & 3);
          af[mt] = *(const short8*)(Ab + (size_t)E * 32 + hh * 8);
        }
#pragma unroll
        for (int nt = 0; nt < 8; ++nt) {
#pragma unroll
          for (int mt = 0; mt < 4; ++mt)
            acc[mt][nt] = __builtin_amdgcn_mfma_f32_16x16x32_bf16(
                af[mt], bfv[nt], acc[mt][nt], 0, 0, 0);
        }
      }
    }
    __syncthreads();
  }
#undef STAGE

  // epilogue: staging LDS dead -> zero lsum in same space
  for (int i = t; i < 19 * 256; i += 256) lsum[i] = 0.f;
  __syncthreads();

  const int* labp = labels + b * 16384 + y * 128;
  float bco[8];
#pragma unroll
  for (int nt = 0; nt < 8; ++nt) bco[nt] = bias[co_w + nt * 16 + lr];
#pragma unroll
  for (int mt = 0; mt < 4; ++mt) {
#pragma unroll
    for (int r = 0; r < 4; ++r) {
      const int lab = labp[wm * 64 + mt * 16 + lg * 4 + r];
#pragma unroll
      for (int nt = 0; nt < 8; ++nt) {
        const float v = tanh_fast(acc[mt][nt][r] + bco[nt]);
        atomicAdd(&lsum[lab * 256 + wn * 128 + nt * 16 + lr], v);
      }
    }
  }
  __syncthreads();
  for (int i = t; i < 19 * 256; i += 256) {
    const float v = lsum[i];
    if (v != 0.f) {
      const int sI = i >> 8, c = i & 255;
      atomicAdd(&sums[((size_t)b * 19 + sI) * 512 + coh * 256 + c], v);
    }
  }
}

// ---------------- finalize: out = cnt>0 ? sums/max(cnt,1) : 0 ----------------
__global__ __launch_bounds__(256) void finalize_kernel(
    const float* __restrict__ sums, const float* __restrict__ cnt,
    float* __restrict__ out) {
  const int i = blockIdx.x * 256 + threadIdx.x;
  if (i >= B * 19 * 512) return;
  const int bs = i >> 9;
  const float c = cnt[bs];
  out[i] = c > 0.f ? sums[i] / fmaxf(c, 1.f) : 0.f;
}

// ---------------------------------------------------------------------------
extern "C" void kernel_launch(void* const* d_in, const int* in_sizes, int n_in,
                              void* d_out, int out_size, void* d_ws,
                              size_t ws_size, hipStream_t stream) {
  const float* input = (const float*)d_in[0];
  const float* segmap = (const float*)d_in[1];
  const float* w0 = (const float*)d_in[2];
  const float* b0 = (const float*)d_in[3];
  const float* w1 = (const float*)d_in[4];
  const float* b1 = (const float*)d_in[5];
  const float* w2 = (const float*)d_in[6];
  const float* b2 = (const float*)d_in[7];
  const float* wt = (const float*)d_in[8];
  const float* bt = (const float*)d_in[9];
  const float* w3 = (const float*)d_in[10];
  const float* b3 = (const float*)d_in[11];
  float* out = (float*)d_out;

  float* ws = (float*)d_ws;
  float* x0 = ws;                                    // 16,777,216 f
  float* x1 = x0 + 16777216;                         //  8,388,608 f
  float* x2 = x1 + 8388608;                          //  4,194,304 f
  unsigned short* X2p = (unsigned short*)(x2 + 4194304);  // 4,326,400 us
  unsigned short* Y = X2p + 4326400;                 // 33,554,432 us
  float* sums = (float*)(Y + 33554432);              //     77,824 f
  float* cnt = sums + 77824;                         //        152 f
  float* ssum = cnt + 152;                           //      2,048 f
  float* ssq = ssum + 2048;                          //      2,048 f
  int* labels = (int*)(ssq + 2048);                  //    131,072 i
  unsigned short* Wb2 = (unsigned short*)(labels + 131072);  // 1,179,648 us
  unsigned short* Wtb2 = Wb2 + 1179648;              //    294,912 us
  unsigned short* Xpad = (unsigned short*)ws;        // 69.2MB over x0+x1 (dead)

  hipMemsetAsync(sums, 0, (77824 + 152 + 2048 + 2048) * sizeof(float), stream);

  wprep_kernel<<<dim3((9 * 512 * 256 + 255) / 256), 256, 0, stream>>>(w3, Wb2);
  wtprep_kernel<<<dim3((9 * 256 * 128 + 255) / 256), 256, 0, stream>>>(wt, Wtb2);
  conv0_kernel<<<dim3(256, B), 256, 0, stream>>>(input, w0, b0, x0);
  inorm_lrelu_kernel<<<dim3(B * 32), 256, 0, stream>>>(x0, 65536);
  conv_s2_kernel<32, 64, 256><<<dim3(64, 2, B), 256, 0, stream>>>(x0, w1, b1, x1);
  inorm_lrelu_kernel<<<dim3(B * 64), 256, 0, stream>>>(x1, 16384);
  conv_s2_kernel<64, 128, 128><<<dim3(16, 4, B), 256, 0, stream>>>(x1, w2, b2, x2);
  inorm_lrelu_kernel<<<dim3(B * 128), 256, 0, stream>>>(x2, 4096);
  transpose_x2_kernel<<<dim3(128, B), 256, 0, stream>>>(x2, X2p);
  zpad_x2_kernel<<<dim3(B), 256, 0, stream>>>(X2p);
  convt_mfma_kernel<<<dim3(2048), 256, 0, stream>>>(X2p, Wtb2, bt, Y);
  inorm_stats_kernel<<<dim3(16, B), 256, 0, stream>>>(Y, ssum, ssq);
  inorm_apply_kernel<<<dim3(16, B), 256, 0, stream>>>(Y, ssum, ssq, Xpad);
  pad_rows_kernel<<<dim3(2 * B), 256, 0, stream>>>(Xpad);
  pad_cols_kernel<<<dim3(2 * B), 256, 0, stream>>>(Xpad);
  label_kernel<<<dim3(64, B), 256, 0, stream>>>(segmap, labels, cnt);
  conv3_mfma_pool_kernel<<<dim3(2048), 256, 0, stream>>>(Xpad, Wb2, b3, labels, sums);
  finalize_kernel<<<dim3((B * 19 * 512 + 255) / 256), 256, 0, stream>>>(sums, cnt, out);
}